// Round 7
// baseline (610.505 us; speedup 1.0000x reference)
//
#include <hip/hip_runtime.h>
#include <hip/hip_bf16.h>
#include <math.h>

#define EPS_ 1e-5f
constexpr int B_ = 4, NA = 64, T_ = 128, D_ = 128, H_ = 8, L_ = 3, DFF = 512, E_ = 65536;
constexpr int DH = D_ / H_;        // 16
constexpr int NN = T_ * NA;        // 8192
constexpr int NTOT = B_ * NA * T_; // 32768
constexpr int QLD = 384;           // packed QKV row stride
constexpr size_t NE_ = (size_t)NTOT * D_;

typedef __bf16 bf16x8 __attribute__((ext_vector_type(8)));
typedef float f32x4 __attribute__((ext_vector_type(4)));

// ---------------- embed: x = hist@W + b ; e = x + posenc ----------------
__global__ __launch_bounds__(256) void embed_kernel(
    const float* __restrict__ hist, const float* __restrict__ w,
    const float* __restrict__ b, float* __restrict__ x, float* __restrict__ e) {
  int idx = blockIdx.x * 256 + threadIdx.x;
  if (idx >= NTOT * D_) return;
  int d = idx & (D_ - 1);
  int r = idx >> 7;
  int t = r & (T_ - 1);
  const float* hp = hist + (size_t)r * 3;
  float acc = b[d];
  acc += hp[0] * w[0 * D_ + d];
  acc += hp[1] * w[1 * D_ + d];
  acc += hp[2] * w[2 * D_ + d];
  x[idx] = acc;
  int p = d >> 1;
  float ang = (float)t * expf(-logf(10000.f) * (2.f * (float)p) / (float)D_);
  float pe = (d & 1) ? cosf(ang) : sinf(ang);
  e[idx] = acc + pe;
}

// ---------------- weight split into FRAGMENT-LINEAR bf16 hi/lo ----------------
__global__ __launch_bounds__(256) void convert_weights(
    const float* __restrict__ wq, const float* __restrict__ wk,
    const float* __restrict__ wv, const float* __restrict__ wo,
    const float* __restrict__ w1, const float* __restrict__ w2,
    __bf16* __restrict__ hi, __bf16* __restrict__ lo) {
  const int LW = 196608;
  int idx = blockIdx.x * 256 + threadIdx.x;
  if (idx >= L_ * LW) return;
  int l = idx / LW;
  int rem = idx - l * LW;
  float src;
  int n, k, K, segoff;
  if (rem < 49152) { // qkv
    n = rem >> 7; k = rem & 127; K = 128; segoff = 0;
    int which = n >> 7, nl = n & 127;
    const float* W = (which == 0) ? wq : (which == 1) ? wk : wv;
    src = W[(size_t)l * 16384 + k * 128 + nl];
  } else if (rem < 65536) { // wo
    int r2 = rem - 49152;
    n = r2 >> 7; k = r2 & 127; K = 128; segoff = 49152;
    src = wo[(size_t)l * 16384 + k * 128 + n];
  } else if (rem < 131072) { // w1
    int r2 = rem - 65536;
    n = r2 >> 7; k = r2 & 127; K = 128; segoff = 65536;
    src = w1[(size_t)l * 65536 + k * 512 + n];
  } else { // w2
    int r2 = rem - 131072;
    n = r2 >> 9; k = r2 & 511; K = 512; segoff = 131072;
    src = w2[(size_t)l * 65536 + k * 128 + n];
  }
  int nt = n >> 4, kt = k >> 5;
  int lane = ((k >> 3) & 3) * 16 + (n & 15);
  int j = k & 7;
  int dst = l * LW + segoff + ((nt * (K / 32) + kt) * 64 + lane) * 8 + j;
  __bf16 h = (__bf16)src;
  hi[dst] = h;
  lo[dst] = (__bf16)(src - (float)h);
}

// ---------------- pack QKV biases ----------------
__global__ __launch_bounds__(256) void bias_pack(
    const float* __restrict__ bq, const float* __restrict__ bk,
    const float* __restrict__ bv, float* __restrict__ pb) {
  int idx = blockIdx.x * 256 + threadIdx.x;
  if (idx >= L_ * QLD) return;
  int l = idx / QLD, n = idx - l * QLD;
  int which = n >> 7, nl = n & 127;
  const float* src = (which == 0) ? bq : (which == 1) ? bk : bv;
  pb[idx] = src[l * 128 + nl];
}

__device__ __forceinline__ void split8(const float* __restrict__ p,
                                       bf16x8& hi, bf16x8& lo) {
  float4 x0 = *(const float4*)p;
  float4 x1 = *(const float4*)(p + 4);
  float xv[8] = {x0.x, x0.y, x0.z, x0.w, x1.x, x1.y, x1.z, x1.w};
#pragma unroll
  for (int j = 0; j < 8; ++j) {
    __bf16 h = (__bf16)xv[j];
    hi[j] = h;
    lo[j] = (__bf16)(xv[j] - (float)h);
  }
}

// identical math to split8, operating on pre-loaded raw float4s (for prefetch)
__device__ __forceinline__ void cvt8(const float4& x0, const float4& x1,
                                     bf16x8& hi, bf16x8& lo) {
  float xv[8] = {x0.x, x0.y, x0.z, x0.w, x1.x, x1.y, x1.z, x1.w};
#pragma unroll
  for (int j = 0; j < 8; ++j) {
    __bf16 h = (__bf16)xv[j];
    hi[j] = h;
    lo[j] = (__bf16)(xv[j] - (float)h);
  }
}

// async global->LDS, 16 B per lane (dest must be wave-uniform; HW adds lane*16)
__device__ __forceinline__ void gload16(const __bf16* g, __bf16* l) {
  __builtin_amdgcn_global_load_lds(
      (const __attribute__((address_space(1))) void*)g,
      (__attribute__((address_space(3))) void*)l, 16, 0, 0);
}

// ---------------- MFMA GEMM, 128x128 tile, frag-linear W, reg double-buffer [r18] ----------------
#define GB_LOADA(buf, kt)                                                                  \
  {                                                                                        \
    _Pragma("unroll") for (int mf_ = 0; mf_ < 4; ++mf_) {                                  \
      const float* p_ = A + (size_t)(row0 + mf_ * 16 + m16) * lda + (kt) * 32 + quad * 8;  \
      ar[buf][mf_][0] = *(const float4*)p_;                                                \
      ar[buf][mf_][1] = *(const float4*)(p_ + 4);                                          \
    }                                                                                      \
  }
#define GB_LOADW(buf, kt)                                                                  \
  {                                                                                        \
    _Pragma("unroll") for (int nf_ = 0; nf_ < 4; ++nf_) {                                  \
      size_t off_ = ((size_t)(ctb + nf_) * (K / 32) + (kt)) * 512 + lane * 8;              \
      bh[buf][nf_] = *(const bf16x8*)(Whi + off_);                                         \
      bl[buf][nf_] = *(const bf16x8*)(Wlo + off_);                                         \
    }                                                                                      \
  }

template <int EPI, int K>
__global__ __launch_bounds__(256, 2) void gemm_big(
    const float* __restrict__ A, int lda,
    const __bf16* __restrict__ Whi, const __bf16* __restrict__ Wlo,
    const float* __restrict__ bias,
    float* __restrict__ C, int ldc) {
  const int wave = threadIdx.x >> 6;
  const int lane = threadIdx.x & 63;
  const int m16 = lane & 15;
  const int quad = lane >> 4;
  const int wrow = wave >> 1, wcol = wave & 1;
  const int row0 = blockIdx.y * 128 + wrow * 64;
  const int col0 = blockIdx.x * 128 + wcol * 64;
  const int ctb = col0 >> 4;

  f32x4 acc[4][4] = {};
  float4 ar[2][4][2];
  bf16x8 bh[2][4], bl[2][4];
  GB_LOADA(0, 0);
  GB_LOADW(0, 0);
#pragma unroll
  for (int kt = 0; kt < K / 32; ++kt) {
    const int cur = kt & 1, nxt = cur ^ 1;
    if (kt < K / 32 - 1) {
      GB_LOADA(nxt, kt + 1);
      GB_LOADW(nxt, kt + 1);
    }
    bf16x8 ahi[4], alo[4];
#pragma unroll
    for (int mf = 0; mf < 4; ++mf)
      cvt8(ar[cur][mf][0], ar[cur][mf][1], ahi[mf], alo[mf]);
#pragma unroll
    for (int mf = 0; mf < 4; ++mf)
#pragma unroll
      for (int nf = 0; nf < 4; ++nf) {
        acc[mf][nf] = __builtin_amdgcn_mfma_f32_16x16x32_bf16(ahi[mf], bh[cur][nf], acc[mf][nf], 0, 0, 0);
        acc[mf][nf] = __builtin_amdgcn_mfma_f32_16x16x32_bf16(ahi[mf], bl[cur][nf], acc[mf][nf], 0, 0, 0);
        acc[mf][nf] = __builtin_amdgcn_mfma_f32_16x16x32_bf16(alo[mf], bh[cur][nf], acc[mf][nf], 0, 0, 0);
      }
  }
#pragma unroll
  for (int mf = 0; mf < 4; ++mf)
#pragma unroll
    for (int nf = 0; nf < 4; ++nf) {
      int c = col0 + nf * 16 + m16;
      float bj = bias[c];
#pragma unroll
      for (int reg = 0; reg < 4; ++reg) {
        int r = row0 + mf * 16 + quad * 4 + reg;
        float v = acc[mf][nf][reg] + bj;
        if (EPI == 1) v = fmaxf(v, 0.f);
        C[(size_t)r * ldc + c] = v;
      }
    }
}
#undef GB_LOADA
#undef GB_LOADW

// ---------------- GEMM + bias + resid + LayerNorm; block 64x128, register A [r12] ----------------
template <int K>
__global__ __launch_bounds__(256) void gemm_ln(
    const float* __restrict__ A, int lda,
    const __bf16* __restrict__ Whi, const __bf16* __restrict__ Wlo,
    const float* __restrict__ bias, const float* __restrict__ resid,
    const float* __restrict__ lng, const float* __restrict__ lnb,
    float* __restrict__ C) {
  const int wave = threadIdx.x >> 6;
  const int lane = threadIdx.x & 63;
  const int m16 = lane & 15;
  const int quad = lane >> 4;
  const int wrow = wave >> 1, wcol = wave & 1;
  const int row0 = blockIdx.y * 64 + wrow * 32;
  const int col0 = wcol * 64;
  const int ctb = wcol * 4;

  f32x4 acc[2][4] = {};
#pragma unroll
  for (int k0 = 0; k0 < K; k0 += 32) {
    bf16x8 ahi[2], alo[2];
#pragma unroll
    for (int mf = 0; mf < 2; ++mf)
      split8(A + (size_t)(row0 + mf * 16 + m16) * lda + k0 + quad * 8, ahi[mf], alo[mf]);
    bf16x8 bhi[4], blo[4];
#pragma unroll
    for (int nf = 0; nf < 4; ++nf) {
      size_t off = ((size_t)(ctb + nf) * (K / 32) + (k0 >> 5)) * 512 + lane * 8;
      bhi[nf] = *(const bf16x8*)(Whi + off);
      blo[nf] = *(const bf16x8*)(Wlo + off);
    }
#pragma unroll
    for (int mf = 0; mf < 2; ++mf)
#pragma unroll
      for (int nf = 0; nf < 4; ++nf) {
        acc[mf][nf] = __builtin_amdgcn_mfma_f32_16x16x32_bf16(ahi[mf], bhi[nf], acc[mf][nf], 0, 0, 0);
        acc[mf][nf] = __builtin_amdgcn_mfma_f32_16x16x32_bf16(ahi[mf], blo[nf], acc[mf][nf], 0, 0, 0);
        acc[mf][nf] = __builtin_amdgcn_mfma_f32_16x16x32_bf16(alo[mf], bhi[nf], acc[mf][nf], 0, 0, 0);
      }
  }
  __shared__ float rs[64][2], rq[64][2];
#pragma unroll
  for (int mf = 0; mf < 2; ++mf)
#pragma unroll
    for (int reg = 0; reg < 4; ++reg) {
      int lr = wrow * 32 + mf * 16 + quad * 4 + reg;
      int gr = blockIdx.y * 64 + lr;
      float s = 0.f, qq = 0.f;
#pragma unroll
      for (int nf = 0; nf < 4; ++nf) {
        int c = col0 + nf * 16 + m16;
        float v = acc[mf][nf][reg] + bias[c] + resid[(size_t)gr * 128 + c];
        acc[mf][nf][reg] = v;
        s += v;
        qq += v * v;
      }
#pragma unroll
      for (int off = 1; off < 16; off <<= 1) {
        s += __shfl_xor(s, off, 64);
        qq += __shfl_xor(qq, off, 64);
      }
      if (m16 == 0) { rs[lr][wcol] = s; rq[lr][wcol] = qq; }
    }
  __syncthreads();
#pragma unroll
  for (int mf = 0; mf < 2; ++mf)
#pragma unroll
    for (int reg = 0; reg < 4; ++reg) {
      int lr = wrow * 32 + mf * 16 + quad * 4 + reg;
      int gr = blockIdx.y * 64 + lr;
      float mean = (rs[lr][0] + rs[lr][1]) * (1.f / 128.f);
      float var = (rq[lr][0] + rq[lr][1]) * (1.f / 128.f) - mean * mean;
      float rstd = rsqrtf(var + EPS_);
#pragma unroll
      for (int nf = 0; nf < 4; ++nf) {
        int c = col0 + nf * 16 + m16;
        C[(size_t)gr * 128 + c] = (acc[mf][nf][reg] - mean) * rstd * lng[c] + lnb[c];
      }
    }
}

// ---------------- FUSED FF1+FF2+LN: async global_load_lds pipeline [r21] ----------------
// r21: r18/r20's register prefetch was defeated twice by the compiler (loads re-sunk to uses
// regardless of VGPR budget -> ~150 serialized ~300cy loads = the 74us). Switch to the guide's
// T3/T4 counted-vmcnt pipeline with global_load_lds: async loads hold NO dest VGPRs, so depth
// is tracked by vmcnt, not the register allocator. Per-wave-private staging slots -> no barriers
// in the steady loop. W layout is already lane*16B-contiguous = perfect linear gload_lds dest.
// FF1: 8 chunks x {8 gloads -> vmcnt(8) -> ds_read -> 24 MFMA}; FF2: 16 chunks x {4 gloads ->
// vmcnt(4) -> 12 MFMA}. MFMA operand bits + per-acc accumulation order identical to r16/r20.
// LDS: ffmid 32x513 f32 (65664 B) + 4 waves x 2 x 4096 bf16 staging (65536 B) = 131200 B
// dynamic -> 1 block/CU, 4 waves. Pipeline (not TLP) hides latency, per m97.
#define FF1_STAGE(c, buf)                                                                    \
  {                                                                                          \
    const int kt_ = (c) >> 1, hf_ = (c) & 1;                                                 \
    __bf16* dst_ = ws + (buf) * 4096;                                                        \
    _Pragma("unroll") for (int j_ = 0; j_ < 4; ++j_) {                                       \
      size_t off_ = ((size_t)(wave * 8 + hf_ * 4 + j_) * 4 + kt_) * 512 + lane * 8;          \
      gload16(W1hi + off_, dst_ + j_ * 512);                                                 \
      gload16(W1lo + off_, dst_ + (4 + j_) * 512);                                           \
    }                                                                                        \
  }
#define FF2_STAGE(kt, buf)                                                                   \
  {                                                                                          \
    __bf16* dst_ = ws + (buf) * 4096;                                                        \
    _Pragma("unroll") for (int nf_ = 0; nf_ < 2; ++nf_) {                                    \
      size_t off_ = ((size_t)(wave * 2 + nf_) * 16 + (kt)) * 512 + lane * 8;                 \
      gload16(W2hi + off_, dst_ + nf_ * 512);                                                \
      gload16(W2lo + off_, dst_ + (2 + nf_) * 512);                                          \
    }                                                                                        \
  }

template <int SDOT>
__global__ __launch_bounds__(256, 1) void ff_fused(
    const float* __restrict__ A, // h1 [M][128]
    const __bf16* __restrict__ W1hi, const __bf16* __restrict__ W1lo,
    const float* __restrict__ b1v,
    const __bf16* __restrict__ W2hi, const __bf16* __restrict__ W2lo,
    const float* __restrict__ b2v, const float* __restrict__ resid,
    const float* __restrict__ lng, const float* __restrict__ lnb,
    float* __restrict__ C,
    const float* __restrict__ bx, float* __restrict__ sdst) {
  extern __shared__ float Amid[]; // [32][513] fp32, then staging region
  const int wave = threadIdx.x >> 6; // 0..3
  const int lane = threadIdx.x & 63;
  const int m16 = lane & 15;
  const int quad = lane >> 4;
  const int grow0 = blockIdx.x * 32;
  __bf16* ws = (__bf16*)(Amid + 32 * 513) + wave * 8192; // 2 slots x 4096 bf16, wave-private

  // ---- A (h1) preload + convert: all 4 kt tiles in registers (64 VGPR; 1 wave/SIMD, no spill)
  bf16x8 ahi[4][2], alo[4][2];
#pragma unroll
  for (int kt = 0; kt < 4; ++kt)
#pragma unroll
    for (int mf = 0; mf < 2; ++mf)
      split8(A + (size_t)(grow0 + mf * 16 + m16) * 128 + kt * 32 + quad * 8, ahi[kt][mf], alo[kt][mf]);
  asm volatile("s_waitcnt vmcnt(0)" ::: "memory"); // clean vmcnt base for counted pipeline

  // ---- phase 1: ffmid = relu(A @ W1 + b1) -> LDS; wave owns cols [wave*128, +128)
  {
    f32x4 acc[2][8] = {};
    FF1_STAGE(0, 0);
#pragma unroll
    for (int c = 0; c < 8; ++c) {
      if (c < 7) {
        FF1_STAGE(c + 1, (c + 1) & 1);
        asm volatile("s_waitcnt vmcnt(8)" ::: "memory"); // chunk c landed; c+1 in flight
      } else {
        asm volatile("s_waitcnt vmcnt(0)" ::: "memory");
      }
      __builtin_amdgcn_sched_barrier(0);
      const __bf16* src = ws + (c & 1) * 4096;
      const int kt = c >> 1, hf = c & 1;
#pragma unroll
      for (int j = 0; j < 4; ++j) {
        bf16x8 wh = *(const bf16x8*)(src + j * 512 + lane * 8);
        bf16x8 wl = *(const bf16x8*)(src + (4 + j) * 512 + lane * 8);
        const int nf = hf * 4 + j;
#pragma unroll
        for (int mf = 0; mf < 2; ++mf) {
          acc[mf][nf] = __builtin_amdgcn_mfma_f32_16x16x32_bf16(ahi[kt][mf], wh, acc[mf][nf], 0, 0, 0);
          acc[mf][nf] = __builtin_amdgcn_mfma_f32_16x16x32_bf16(ahi[kt][mf], wl, acc[mf][nf], 0, 0, 0);
          acc[mf][nf] = __builtin_amdgcn_mfma_f32_16x16x32_bf16(alo[kt][mf], wh, acc[mf][nf], 0, 0, 0);
        }
      }
    }
#pragma unroll
    for (int mf = 0; mf < 2; ++mf)
#pragma unroll
      for (int nf = 0; nf < 8; ++nf) {
        int c = wave * 128 + nf * 16 + m16;
        float bj = b1v[c];
#pragma unroll
        for (int reg = 0; reg < 4; ++reg) {
          int r = mf * 16 + quad * 4 + reg;
          Amid[r * 513 + c] = fmaxf(acc[mf][nf][reg] + bj, 0.f);
        }
      }
  }
  __syncthreads(); // drains vmcnt too (compiler emits full waitcnt before s_barrier)

  // ---- phase 2: out = ffmid @ W2 (K=512); ffmid from LDS, W2 via async pipeline
  f32x4 acc2[2][2] = {};
  FF2_STAGE(0, 0);
#pragma unroll
  for (int kt = 0; kt < 16; ++kt) {
    if (kt < 15) {
      FF2_STAGE(kt + 1, (kt + 1) & 1);
      asm volatile("s_waitcnt vmcnt(4)" ::: "memory");
    } else {
      asm volatile("s_waitcnt vmcnt(0)" ::: "memory");
    }
    __builtin_amdgcn_sched_barrier(0);
    const __bf16* src = ws + (kt & 1) * 4096;
    bf16x8 phi[2], plo[2];
#pragma unroll
    for (int mf = 0; mf < 2; ++mf)
      split8(&Amid[(mf * 16 + m16) * 513 + kt * 32 + quad * 8], phi[mf], plo[mf]);
#pragma unroll
    for (int nf = 0; nf < 2; ++nf) {
      bf16x8 wh = *(const bf16x8*)(src + nf * 512 + lane * 8);
      bf16x8 wl = *(const bf16x8*)(src + (2 + nf) * 512 + lane * 8);
#pragma unroll
      for (int mf = 0; mf < 2; ++mf) {
        acc2[mf][nf] = __builtin_amdgcn_mfma_f32_16x16x32_bf16(phi[mf], wh, acc2[mf][nf], 0, 0, 0);
        acc2[mf][nf] = __builtin_amdgcn_mfma_f32_16x16x32_bf16(phi[mf], wl, acc2[mf][nf], 0, 0, 0);
        acc2[mf][nf] = __builtin_amdgcn_mfma_f32_16x16x32_bf16(plo[mf], wh, acc2[mf][nf], 0, 0, 0);
      }
    }
  }

  // ---- epilogue: bias + resid + LN (+ optional fused gating dot); 4-way partials
  __shared__ float rs[32][4], rq[32][4], sd[32][4];
  const int col0 = wave * 32;
#pragma unroll
  for (int mf = 0; mf < 2; ++mf)
#pragma unroll
    for (int reg = 0; reg < 4; ++reg) {
      int lr = mf * 16 + quad * 4 + reg;
      int gr = grow0 + lr;
      float s = 0.f, qq = 0.f;
#pragma unroll
      for (int nf = 0; nf < 2; ++nf) {
        int c = col0 + nf * 16 + m16;
        float v = acc2[mf][nf][reg] + b2v[c] + resid[(size_t)gr * 128 + c];
        acc2[mf][nf][reg] = v;
        s += v;
        qq += v * v;
      }
#pragma unroll
      for (int off = 1; off < 16; off <<= 1) {
        s += __shfl_xor(s, off, 64);
        qq += __shfl_xor(qq, off, 64);
      }
      if (m16 == 0) { rs[lr][wave] = s; rq[lr][wave] = qq; }
    }
  __syncthreads();
#pragma unroll
  for (int mf = 0; mf < 2; ++mf)
#pragma unroll
    for (int reg = 0; reg < 4; ++reg) {
      int lr = mf * 16 + quad * 4 + reg;
      int gr = grow0 + lr;
      float mean = (rs[lr][0] + rs[lr][1] + rs[lr][2] + rs[lr][3]) * (1.f / 128.f);
      float var = (rq[lr][0] + rq[lr][1] + rq[lr][2] + rq[lr][3]) * (1.f / 128.f) - mean * mean;
      float rstd = rsqrtf(var + EPS_);
      float sdp = 0.f;
#pragma unroll
      for (int nf = 0; nf < 2; ++nf) {
        int c = col0 + nf * 16 + m16;
        float v = (acc2[mf][nf][reg] - mean) * rstd * lng[c] + lnb[c];
        C[(size_t)gr * 128 + c] = v;
        if (SDOT) sdp += v * bx[(size_t)gr * 128 + c];
      }
      if (SDOT) {
#pragma unroll
        for (int off = 1; off < 16; off <<= 1) sdp += __shfl_xor(sdp, off, 64);
        if (m16 == 0) sd[lr][wave] = sdp;
      }
    }
  if (SDOT) {
    __syncthreads();
    if (threadIdx.x < 32) {
      int lr = threadIdx.x;
      int gr = grow0 + lr;
      float sv = sd[lr][0] + sd[lr][1] + sd[lr][2] + sd[lr][3];
      int t = gr & (T_ - 1);
      int bn = gr >> 7;
      int n = bn & (NA - 1);
      int b = bn >> 6;
      sdst[(size_t)b * NN + t * NA + n] = sv;
    }
  }
}
#undef FF1_STAGE
#undef FF2_STAGE

// ---------------- MFMA attention v2: K/V staged once per block in frag-linear LDS ----------------
__global__ __launch_bounds__(256) void attn_mfma(float* __restrict__ qkv) {
  const int h = blockIdx.x & (H_ - 1);
  const int bn = blockIdx.x >> 3;
  const int wave = threadIdx.x >> 6;
  const int lane = threadIdx.x & 63;
  const int m16 = lane & 15;
  const int quad = lane >> 4;
  const int row0 = wave * 32;
  const float* Qb = qkv + (size_t)bn * T_ * QLD + h * DH;
  const float* Kb = Qb + 128;
  const float* Vb = Qb + 256;
  float* Ob = (float*)Vb;

  __shared__ __bf16 Plds[4][32][136];
  __shared__ __bf16 KH[8][32][8], KL[8][32][8]; // K frag-linear: [nf][quad*16+t15][dh&7]
  __shared__ __bf16 VH[4][64][8], VL[4][64][8]; // V frag-linear: [kc][kq*16+dh][t&7]

  // cooperative stage: K and V (128 rows x 16 dh each), coalesced float4, hi/lo split
  for (int u = threadIdx.x; u < 1024; u += 256) {
    int isV = u >> 9;
    int r2 = u & 511;
    int t = r2 >> 2, c4 = r2 & 3;
    float4 v = *(const float4*)((isV ? Vb : Kb) + (size_t)t * QLD + c4 * 4);
    float xv[4] = {v.x, v.y, v.z, v.w};
#pragma unroll
    for (int i = 0; i < 4; ++i) {
      int dh = c4 * 4 + i;
      __bf16 hh = (__bf16)xv[i];
      __bf16 ll = (__bf16)(xv[i] - (float)hh);
      if (isV) {
        int kc = t >> 5, rem = t & 31;
        int vl = (rem >> 3) * 16 + dh;
        VH[kc][vl][rem & 7] = hh;
        VL[kc][vl][rem & 7] = ll;
      } else {
        int nf = t >> 4;
        int kl = (dh >> 3) * 16 + (t & 15);
        KH[nf][kl][dh & 7] = hh;
        KL[nf][kl][dh & 7] = ll;
      }
    }
  }

  // Q A-frags from global (registers, zero-pad quad>=2)
  bf16x8 qhi[2], qlo[2];
#pragma unroll
  for (int mf = 0; mf < 2; ++mf) {
    if (quad < 2) {
      split8(Qb + (size_t)(row0 + mf * 16 + m16) * QLD + quad * 8, qhi[mf], qlo[mf]);
    } else {
#pragma unroll
      for (int j = 0; j < 8; ++j) { qhi[mf][j] = (__bf16)0.f; qlo[mf][j] = (__bf16)0.f; }
    }
  }
  __syncthreads(); // staging complete

  f32x4 acc[2][8] = {};
#pragma unroll
  for (int nf = 0; nf < 8; ++nf) {
    bf16x8 khi, klo;
    if (quad < 2) {
      khi = *(const bf16x8*)&KH[nf][lane][0]; // lane in [0,32)
      klo = *(const bf16x8*)&KL[nf][lane][0];
    } else {
#pragma unroll
      for (int j = 0; j < 8; ++j) { khi[j] = (__bf16)0.f; klo[j] = (__bf16)0.f; }
    }
#pragma unroll
    for (int mf = 0; mf < 2; ++mf) {
      acc[mf][nf] = __builtin_amdgcn_mfma_f32_16x16x32_bf16(qhi[mf], khi, acc[mf][nf], 0, 0, 0);
      acc[mf][nf] = __builtin_amdgcn_mfma_f32_16x16x32_bf16(qhi[mf], klo, acc[mf][nf], 0, 0, 0);
      acc[mf][nf] = __builtin_amdgcn_mfma_f32_16x16x32_bf16(qlo[mf], khi, acc[mf][nf], 0, 0, 0);
    }
  }

  const float scale = 0.25f;
#pragma unroll
  for (int mf = 0; mf < 2; ++mf)
#pragma unroll
    for (int reg = 0; reg < 4; ++reg) {
      float mx = -1e30f;
#pragma unroll
      for (int nf = 0; nf < 8; ++nf) mx = fmaxf(mx, acc[mf][nf][reg]);
#pragma unroll
      for (int off = 1; off < 16; off <<= 1) mx = fmaxf(mx, __shfl_xor(mx, off, 64));
      float sum = 0.f;
#pragma unroll
      for (int nf = 0; nf < 8; ++nf) {
        float e = __expf((acc[mf][nf][reg] - mx) * scale);
        acc[mf][nf][reg] = e;
        sum += e;
      }
#pragma unroll
      for (int off = 1; off < 16; off <<= 1) sum += __shfl_xor(sum, off, 64);
      float inv = 1.f / sum;
#pragma unroll
      for (int nf = 0; nf < 8; ++nf) acc[mf][nf][reg] *= inv;
    }

#pragma unroll
  for (int mf = 0; mf < 2; ++mf)
#pragma unroll
    for (int nf = 0; nf < 8; ++nf)
#pragma unroll
      for (int reg = 0; reg < 4; ++reg)
        Plds[wave][mf * 16 + quad * 4 + reg][nf * 16 + m16] = (__bf16)acc[mf][nf][reg];

  f32x4 oacc[2] = {};
#pragma unroll
  for (int kc = 0; kc < 4; ++kc) {
    bf16x8 pa0 = *(const bf16x8*)&Plds[wave][m16][kc * 32 + quad * 8];
    bf16x8 pa1 = *(const bf16x8*)&Plds[wave][16 + m16][kc * 32 + quad * 8];
    bf16x8 vhi = *(const bf16x8*)&VH[kc][lane][0];
    bf16x8 vlo = *(const bf16x8*)&VL[kc][lane][0];
    oacc[0] = __builtin_amdgcn_mfma_f32_16x16x32_bf16(pa0, vhi, oacc[0], 0, 0, 0);
    oacc[0] = __builtin_amdgcn_mfma_f32_16x16x32_bf16(pa0, vlo, oacc[0], 0, 0, 0);
    oacc[1] = __builtin_amdgcn_mfma_f32_16x16x32_bf16(pa1, vhi, oacc[1], 0, 0, 0);
    oacc[1] = __builtin_amdgcn_mfma_f32_16x16x32_bf16(pa1, vlo, oacc[1], 0, 0, 0);
  }

  // Global V slice was consumed during staging (before the barrier) — O write is safe.
#pragma unroll
  for (int mf = 0; mf < 2; ++mf)
#pragma unroll
    for (int reg = 0; reg < 4; ++reg) {
      int r = row0 + mf * 16 + quad * 4 + reg;
      Ob[(size_t)r * QLD + m16] = oacc[mf][reg];
    }
}

// ---------------- edge scatter ----------------
__global__ __launch_bounds__(256) void scatter_kernel(
    const float* __restrict__ s, const int* __restrict__ ei,
    const float* __restrict__ ew, float* __restrict__ g) {
  int idx = blockIdx.x * 256 + threadIdx.x;
  if (idx >= B_ * E_) return;
  int b = idx >> 16;
  int e = idx & (E_ - 1);
  int src = ei[(size_t)b * 2 * E_ + e];
  int dst = ei[(size_t)b * 2 * E_ + E_ + e];
  float w = ew[(size_t)b * E_ + e];
  atomicAdd(&g[(size_t)b * NN + dst], w * s[(size_t)b * NN + src]);
}

// ---------------- partial sums for global mean/var ----------------
__global__ __launch_bounds__(256) void stats_partial(
    const float* __restrict__ g, float* __restrict__ st) {
  int i = blockIdx.x * 256 + threadIdx.x;
  float v = g[i];
  float sum = v, sq = v * v;
#pragma unroll
  for (int off = 32; off; off >>= 1) {
    sum += __shfl_down(sum, off, 64);
    sq += __shfl_down(sq, off, 64);
  }
  __shared__ float s1[4], s2[4];
  int w = threadIdx.x >> 6;
  if ((threadIdx.x & 63) == 0) { s1[w] = sum; s2[w] = sq; }
  __syncthreads();
  if (threadIdx.x == 0) {
    atomicAdd(&st[0], s1[0] + s1[1] + s1[2] + s1[3]);
    atomicAdd(&st[1], s2[0] + s2[1] + s2[2] + s2[3]);
  }
}

// ---------------- final (fp32 out) ----------------
__global__ __launch_bounds__(256) void final_kernel(
    const float* __restrict__ g, const float* __restrict__ st,
    const float* __restrict__ bng, const float* __restrict__ bnb,
    const float* __restrict__ lw, const float* __restrict__ lb,
    float* __restrict__ out) {
  int idx = blockIdx.x * 256 + threadIdx.x;
  if (idx >= NTOT * D_) return;
  int d = idx & (D_ - 1);
  int r = idx >> 7;
  int t = r & (T_ - 1);
  int bn = r >> 7;
  int n = bn & (NA - 1);
  int b = bn >> 6;
  const float invn = 1.f / (float)(B_ * NN);
  float m = st[0] * invn;
  float var = st[1] * invn - m * m;
  float rs = rsqrtf(var + EPS_);
  float gv = g[(size_t)b * NN + t * NA + n];
  float val = (gv - m) * rs * bng[0] + bnb[0];
  out[idx] = val * lw[d] + lb[d];
}

extern "C" void kernel_launch(void* const* d_in, const int* in_sizes, int n_in,
                              void* d_out, int out_size, void* d_ws, size_t ws_size,
                              hipStream_t stream) {
  const float* hist = (const float*)d_in[0];
  const int* eidx = (const int*)d_in[1];
  const float* ew = (const float*)d_in[2];
  const float* hw = (const float*)d_in[3];
  const float* hb = (const float*)d_in[4];
  const float* wq = (const float*)d_in[5];
  const float* bq = (const float*)d_in[6];
  const float* wk = (const float*)d_in[7];
  const float* bk = (const float*)d_in[8];
  const float* wv = (const float*)d_in[9];
  const float* bv = (const float*)d_in[10];
  const float* wo = (const float*)d_in[11];
  const float* bo = (const float*)d_in[12];
  const float* ln1g = (const float*)d_in[13];
  const float* ln1b = (const float*)d_in[14];
  const float* w1 = (const float*)d_in[15];
  const float* b1 = (const float*)d_in[16];
  const float* w2 = (const float*)d_in[17];
  const float* b2 = (const float*)d_in[18];
  const float* ln2g = (const float*)d_in[19];
  const float* ln2b = (const float*)d_in[20];
  const float* bng = (const float*)d_in[21];
  const float* bnb = (const float*)d_in[22];
  const float* lgw = (const float*)d_in[23];
  const float* lgb = (const float*)d_in[24];
  float* out = (float*)d_out;

  float* ws = (float*)d_ws;
  const size_t NE = NE_;
  float* bx = ws + 0 * NE;
  float* be = ws + 1 * NE;
  float* h1 = ws + 2 * NE;
  float* qkv = ws + 3 * NE;   // 3NE, [row][384]
  float* bs_ = ws + 7 * NE;
  float* bg_ = bs_ + NTOT;
  float* bst = bg_ + NTOT;
  float* pbias = bst + 2;
  const int LW = 196608;
  __bf16* whiB = (__bf16*)(pbias + L_ * QLD);
  __bf16* wloB = whiB + (size_t)L_ * LW;

  // dynamic LDS: ffmid 32*513*4 = 65664 B + staging 4 waves * 2 * 4096 bf16 = 65536 B
  const size_t ffshm = (size_t)32 * 513 * sizeof(float) + (size_t)4 * 2 * 4096 * sizeof(__bf16);
  // One-time opt-in for >64 KiB dynamic LDS (host-side, graph-capture-safe).
  static bool ff_attr_done = false;
  if (!ff_attr_done) {
    (void)hipFuncSetAttribute(reinterpret_cast<const void*>(&ff_fused<0>),
                              hipFuncAttributeMaxDynamicSharedMemorySize, (int)ffshm);
    (void)hipFuncSetAttribute(reinterpret_cast<const void*>(&ff_fused<1>),
                              hipFuncAttributeMaxDynamicSharedMemorySize, (int)ffshm);
    ff_attr_done = true;
  }

  convert_weights<<<(L_ * LW + 255) / 256, 256, 0, stream>>>(
      wq, wk, wv, wo, w1, w2, whiB, wloB);
  bias_pack<<<(L_ * QLD + 255) / 256, 256, 0, stream>>>(bq, bk, bv, pbias);
  embed_kernel<<<(NTOT * D_) / 256, 256, 0, stream>>>(hist, hw, hb, bx, be);

  for (int l = 0; l < L_; ++l) {
    const __bf16* hiL = whiB + (size_t)l * LW;
    const __bf16* loL = wloB + (size_t)l * LW;
    gemm_big<0, 128><<<dim3(3, NTOT / 128), 256, 0, stream>>>(
        be, 128, hiL, loL, pbias + l * QLD, qkv, QLD);
    attn_mfma<<<B_ * NA * H_, 256, 0, stream>>>(qkv);
    gemm_ln<128><<<dim3(1, NTOT / 64), 256, 0, stream>>>(
        qkv + 256, QLD, hiL + 49152, loL + 49152, bo + l * D_, be,
        ln1g + l * D_, ln1b + l * D_, h1);
    if (l < L_ - 1) {
      ff_fused<0><<<NTOT / 32, 256, ffshm, stream>>>(
          h1, hiL + 65536, loL + 65536, b1 + l * DFF,
          hiL + 131072, loL + 131072, b2 + l * D_, h1,
          ln2g + l * D_, ln2b + l * D_, be, nullptr, nullptr);
    } else {
      ff_fused<1><<<NTOT / 32, 256, ffshm, stream>>>(
          h1, hiL + 65536, loL + 65536, b1 + l * DFF,
          hiL + 131072, loL + 131072, b2 + l * D_, h1,
          ln2g + l * D_, ln2b + l * D_, be, bx, bs_);
    }
  }

  hipMemsetAsync(bg_, 0, ((size_t)B_ * NN + 2) * sizeof(float), stream);
  scatter_kernel<<<(B_ * E_) / 256, 256, 0, stream>>>(bs_, eidx, ew, bg_);
  stats_partial<<<(B_ * NN) / 256, 256, 0, stream>>>(bg_, bst);
  final_kernel<<<(NTOT * D_) / 256, 256, 0, stream>>>(bg_, bst, bng, bnb, lgw, lgb, out);
}

// Round 8
// 554.679 us; speedup vs baseline: 1.1006x; 1.1006x over previous
//
#include <hip/hip_runtime.h>
#include <hip/hip_bf16.h>
#include <math.h>

#define EPS_ 1e-5f
constexpr int B_ = 4, NA = 64, T_ = 128, D_ = 128, H_ = 8, L_ = 3, DFF = 512, E_ = 65536;
constexpr int DH = D_ / H_;        // 16
constexpr int NN = T_ * NA;        // 8192
constexpr int NTOT = B_ * NA * T_; // 32768
constexpr int QLD = 384;           // packed QKV row stride
constexpr size_t NE_ = (size_t)NTOT * D_;

typedef __bf16 bf16x8 __attribute__((ext_vector_type(8)));
typedef float f32x4 __attribute__((ext_vector_type(4)));

// ---------------- embed: x = hist@W + b ; e = x + posenc ----------------
__global__ __launch_bounds__(256) void embed_kernel(
    const float* __restrict__ hist, const float* __restrict__ w,
    const float* __restrict__ b, float* __restrict__ x, float* __restrict__ e) {
  int idx = blockIdx.x * 256 + threadIdx.x;
  if (idx >= NTOT * D_) return;
  int d = idx & (D_ - 1);
  int r = idx >> 7;
  int t = r & (T_ - 1);
  const float* hp = hist + (size_t)r * 3;
  float acc = b[d];
  acc += hp[0] * w[0 * D_ + d];
  acc += hp[1] * w[1 * D_ + d];
  acc += hp[2] * w[2 * D_ + d];
  x[idx] = acc;
  int p = d >> 1;
  float ang = (float)t * expf(-logf(10000.f) * (2.f * (float)p) / (float)D_);
  float pe = (d & 1) ? cosf(ang) : sinf(ang);
  e[idx] = acc + pe;
}

// ---------------- weight split into FRAGMENT-LINEAR bf16 hi/lo ----------------
__global__ __launch_bounds__(256) void convert_weights(
    const float* __restrict__ wq, const float* __restrict__ wk,
    const float* __restrict__ wv, const float* __restrict__ wo,
    const float* __restrict__ w1, const float* __restrict__ w2,
    __bf16* __restrict__ hi, __bf16* __restrict__ lo) {
  const int LW = 196608;
  int idx = blockIdx.x * 256 + threadIdx.x;
  if (idx >= L_ * LW) return;
  int l = idx / LW;
  int rem = idx - l * LW;
  float src;
  int n, k, K, segoff;
  if (rem < 49152) { // qkv
    n = rem >> 7; k = rem & 127; K = 128; segoff = 0;
    int which = n >> 7, nl = n & 127;
    const float* W = (which == 0) ? wq : (which == 1) ? wk : wv;
    src = W[(size_t)l * 16384 + k * 128 + nl];
  } else if (rem < 65536) { // wo
    int r2 = rem - 49152;
    n = r2 >> 7; k = r2 & 127; K = 128; segoff = 49152;
    src = wo[(size_t)l * 16384 + k * 128 + n];
  } else if (rem < 131072) { // w1
    int r2 = rem - 65536;
    n = r2 >> 7; k = r2 & 127; K = 128; segoff = 65536;
    src = w1[(size_t)l * 65536 + k * 512 + n];
  } else { // w2
    int r2 = rem - 131072;
    n = r2 >> 9; k = r2 & 511; K = 512; segoff = 131072;
    src = w2[(size_t)l * 65536 + k * 128 + n];
  }
  int nt = n >> 4, kt = k >> 5;
  int lane = ((k >> 3) & 3) * 16 + (n & 15);
  int j = k & 7;
  int dst = l * LW + segoff + ((nt * (K / 32) + kt) * 64 + lane) * 8 + j;
  __bf16 h = (__bf16)src;
  hi[dst] = h;
  lo[dst] = (__bf16)(src - (float)h);
}

// ---------------- pack QKV biases ----------------
__global__ __launch_bounds__(256) void bias_pack(
    const float* __restrict__ bq, const float* __restrict__ bk,
    const float* __restrict__ bv, float* __restrict__ pb) {
  int idx = blockIdx.x * 256 + threadIdx.x;
  if (idx >= L_ * QLD) return;
  int l = idx / QLD, n = idx - l * QLD;
  int which = n >> 7, nl = n & 127;
  const float* src = (which == 0) ? bq : (which == 1) ? bk : bv;
  pb[idx] = src[l * 128 + nl];
}

__device__ __forceinline__ void split8(const float* __restrict__ p,
                                       bf16x8& hi, bf16x8& lo) {
  float4 x0 = *(const float4*)p;
  float4 x1 = *(const float4*)(p + 4);
  float xv[8] = {x0.x, x0.y, x0.z, x0.w, x1.x, x1.y, x1.z, x1.w};
#pragma unroll
  for (int j = 0; j < 8; ++j) {
    __bf16 h = (__bf16)xv[j];
    hi[j] = h;
    lo[j] = (__bf16)(xv[j] - (float)h);
  }
}

// ---------------- MFMA GEMM, 64x128 tile (wave 32x64), frag-linear W [r22] ----------------
// r22: revert the FF-fusion arc (7 rounds, neutral-to-negative vs the r0 538us baseline) and
// attack the counter-diagnosed limiter instead: all GEMMs ran at ~20% occupancy, grid-limited
// (QKV: 768 blocks = 12 waves/CU ceiling). Half the row-tile -> 2x blocks: QKV 1536, FF1 2048
// blocks -> 24-32 waves/CU possible. Inner loop = gemm_ln's proven structure (split8 direct,
// no dbuf — reg-dbuf was twice-proven neutral). Per-element accumulation order unchanged.
template <int EPI, int K>
__global__ __launch_bounds__(256) void gemm_small(
    const float* __restrict__ A, int lda,
    const __bf16* __restrict__ Whi, const __bf16* __restrict__ Wlo,
    const float* __restrict__ bias,
    float* __restrict__ C, int ldc) {
  const int wave = threadIdx.x >> 6;
  const int lane = threadIdx.x & 63;
  const int m16 = lane & 15;
  const int quad = lane >> 4;
  const int wrow = wave >> 1, wcol = wave & 1;
  const int row0 = blockIdx.y * 64 + wrow * 32;
  const int col0 = blockIdx.x * 128 + wcol * 64;
  const int ctb = col0 >> 4;

  f32x4 acc[2][4] = {};
#pragma unroll
  for (int k0 = 0; k0 < K; k0 += 32) {
    bf16x8 ahi[2], alo[2];
#pragma unroll
    for (int mf = 0; mf < 2; ++mf)
      split8(A + (size_t)(row0 + mf * 16 + m16) * lda + k0 + quad * 8, ahi[mf], alo[mf]);
    bf16x8 bhi[4], blo[4];
#pragma unroll
    for (int nf = 0; nf < 4; ++nf) {
      size_t off = ((size_t)(ctb + nf) * (K / 32) + (k0 >> 5)) * 512 + lane * 8;
      bhi[nf] = *(const bf16x8*)(Whi + off);
      blo[nf] = *(const bf16x8*)(Wlo + off);
    }
#pragma unroll
    for (int mf = 0; mf < 2; ++mf)
#pragma unroll
      for (int nf = 0; nf < 4; ++nf) {
        acc[mf][nf] = __builtin_amdgcn_mfma_f32_16x16x32_bf16(ahi[mf], bhi[nf], acc[mf][nf], 0, 0, 0);
        acc[mf][nf] = __builtin_amdgcn_mfma_f32_16x16x32_bf16(ahi[mf], blo[nf], acc[mf][nf], 0, 0, 0);
        acc[mf][nf] = __builtin_amdgcn_mfma_f32_16x16x32_bf16(alo[mf], bhi[nf], acc[mf][nf], 0, 0, 0);
      }
  }
#pragma unroll
  for (int mf = 0; mf < 2; ++mf)
#pragma unroll
    for (int nf = 0; nf < 4; ++nf) {
      int c = col0 + nf * 16 + m16;
      float bj = bias[c];
#pragma unroll
      for (int reg = 0; reg < 4; ++reg) {
        int r = row0 + mf * 16 + quad * 4 + reg;
        float v = acc[mf][nf][reg] + bj;
        if (EPI == 1) v = fmaxf(v, 0.f);
        C[(size_t)r * ldc + c] = v;
      }
    }
}

// ---------------- GEMM + bias + resid + LayerNorm; block 64x128, register A [r12] ----------------
template <int K>
__global__ __launch_bounds__(256) void gemm_ln(
    const float* __restrict__ A, int lda,
    const __bf16* __restrict__ Whi, const __bf16* __restrict__ Wlo,
    const float* __restrict__ bias, const float* __restrict__ resid,
    const float* __restrict__ lng, const float* __restrict__ lnb,
    float* __restrict__ C) {
  const int wave = threadIdx.x >> 6;
  const int lane = threadIdx.x & 63;
  const int m16 = lane & 15;
  const int quad = lane >> 4;
  const int wrow = wave >> 1, wcol = wave & 1;
  const int row0 = blockIdx.y * 64 + wrow * 32;
  const int col0 = wcol * 64;
  const int ctb = wcol * 4;

  f32x4 acc[2][4] = {};
#pragma unroll
  for (int k0 = 0; k0 < K; k0 += 32) {
    bf16x8 ahi[2], alo[2];
#pragma unroll
    for (int mf = 0; mf < 2; ++mf)
      split8(A + (size_t)(row0 + mf * 16 + m16) * lda + k0 + quad * 8, ahi[mf], alo[mf]);
    bf16x8 bhi[4], blo[4];
#pragma unroll
    for (int nf = 0; nf < 4; ++nf) {
      size_t off = ((size_t)(ctb + nf) * (K / 32) + (k0 >> 5)) * 512 + lane * 8;
      bhi[nf] = *(const bf16x8*)(Whi + off);
      blo[nf] = *(const bf16x8*)(Wlo + off);
    }
#pragma unroll
    for (int mf = 0; mf < 2; ++mf)
#pragma unroll
      for (int nf = 0; nf < 4; ++nf) {
        acc[mf][nf] = __builtin_amdgcn_mfma_f32_16x16x32_bf16(ahi[mf], bhi[nf], acc[mf][nf], 0, 0, 0);
        acc[mf][nf] = __builtin_amdgcn_mfma_f32_16x16x32_bf16(ahi[mf], blo[nf], acc[mf][nf], 0, 0, 0);
        acc[mf][nf] = __builtin_amdgcn_mfma_f32_16x16x32_bf16(alo[mf], bhi[nf], acc[mf][nf], 0, 0, 0);
      }
  }
  __shared__ float rs[64][2], rq[64][2];
#pragma unroll
  for (int mf = 0; mf < 2; ++mf)
#pragma unroll
    for (int reg = 0; reg < 4; ++reg) {
      int lr = wrow * 32 + mf * 16 + quad * 4 + reg;
      int gr = blockIdx.y * 64 + lr;
      float s = 0.f, qq = 0.f;
#pragma unroll
      for (int nf = 0; nf < 4; ++nf) {
        int c = col0 + nf * 16 + m16;
        float v = acc[mf][nf][reg] + bias[c] + resid[(size_t)gr * 128 + c];
        acc[mf][nf][reg] = v;
        s += v;
        qq += v * v;
      }
#pragma unroll
      for (int off = 1; off < 16; off <<= 1) {
        s += __shfl_xor(s, off, 64);
        qq += __shfl_xor(qq, off, 64);
      }
      if (m16 == 0) { rs[lr][wcol] = s; rq[lr][wcol] = qq; }
    }
  __syncthreads();
#pragma unroll
  for (int mf = 0; mf < 2; ++mf)
#pragma unroll
    for (int reg = 0; reg < 4; ++reg) {
      int lr = wrow * 32 + mf * 16 + quad * 4 + reg;
      int gr = blockIdx.y * 64 + lr;
      float mean = (rs[lr][0] + rs[lr][1]) * (1.f / 128.f);
      float var = (rq[lr][0] + rq[lr][1]) * (1.f / 128.f) - mean * mean;
      float rstd = rsqrtf(var + EPS_);
#pragma unroll
      for (int nf = 0; nf < 4; ++nf) {
        int c = col0 + nf * 16 + m16;
        C[(size_t)gr * 128 + c] = (acc[mf][nf][reg] - mean) * rstd * lng[c] + lnb[c];
      }
    }
}

// ---------------- FF2 + LN (staged A, K=512) [r12]; SDOT fuses gating dot [r15] ----------------
// (r0-proven kernel, reverted verbatim after the fusion arc proved neutral.)
template <int SDOT>
__global__ __launch_bounds__(256) void ff2_ln(
    const float* __restrict__ A, // ffmid [M][512]
    const __bf16* __restrict__ Whi, const __bf16* __restrict__ Wlo,
    const float* __restrict__ bias, const float* __restrict__ resid,
    const float* __restrict__ lng, const float* __restrict__ lnb,
    float* __restrict__ C,
    const float* __restrict__ bx, float* __restrict__ sdst) {
  const int wave = threadIdx.x >> 6;
  const int lane = threadIdx.x & 63;
  const int m16 = lane & 15;
  const int quad = lane >> 4;
  const int wrow = wave >> 1, wcol = wave & 1;
  const int grow0 = blockIdx.y * 64;
  const int lrow0 = wrow * 32;
  const int col0 = wcol * 64;
  const int ctb = wcol * 4;

  __shared__ float As[64][129];

  f32x4 acc[2][4] = {};
  for (int kc = 0; kc < 4; ++kc) {
    if (kc) __syncthreads();
#pragma unroll
    for (int u = 0; u < 8; ++u) {
      int unit = threadIdx.x + u * 256;
      int r = unit >> 5, c4 = unit & 31;
      float4 v = *(const float4*)(A + (size_t)(grow0 + r) * 512 + kc * 128 + c4 * 4);
      As[r][c4 * 4 + 0] = v.x;
      As[r][c4 * 4 + 1] = v.y;
      As[r][c4 * 4 + 2] = v.z;
      As[r][c4 * 4 + 3] = v.w;
    }
    __syncthreads();
#pragma unroll
    for (int kt = 0; kt < 4; ++kt) {
      bf16x8 ahi[2], alo[2];
#pragma unroll
      for (int mf = 0; mf < 2; ++mf)
        split8(&As[lrow0 + mf * 16 + m16][kt * 32 + quad * 8], ahi[mf], alo[mf]);
      bf16x8 bhi[4], blo[4];
#pragma unroll
      for (int nf = 0; nf < 4; ++nf) {
        size_t off = ((size_t)(ctb + nf) * 16 + (kc * 4 + kt)) * 512 + lane * 8;
        bhi[nf] = *(const bf16x8*)(Whi + off);
        blo[nf] = *(const bf16x8*)(Wlo + off);
      }
#pragma unroll
      for (int mf = 0; mf < 2; ++mf)
#pragma unroll
        for (int nf = 0; nf < 4; ++nf) {
          acc[mf][nf] = __builtin_amdgcn_mfma_f32_16x16x32_bf16(ahi[mf], bhi[nf], acc[mf][nf], 0, 0, 0);
          acc[mf][nf] = __builtin_amdgcn_mfma_f32_16x16x32_bf16(ahi[mf], blo[nf], acc[mf][nf], 0, 0, 0);
          acc[mf][nf] = __builtin_amdgcn_mfma_f32_16x16x32_bf16(alo[mf], bhi[nf], acc[mf][nf], 0, 0, 0);
        }
    }
  }
  __shared__ float rs[64][2], rq[64][2];
  __shared__ float sd[64][2];
#pragma unroll
  for (int mf = 0; mf < 2; ++mf)
#pragma unroll
    for (int reg = 0; reg < 4; ++reg) {
      int lr = lrow0 + mf * 16 + quad * 4 + reg;
      int gr = grow0 + lr;
      float s = 0.f, qq = 0.f;
#pragma unroll
      for (int nf = 0; nf < 4; ++nf) {
        int c = col0 + nf * 16 + m16;
        float v = acc[mf][nf][reg] + bias[c] + resid[(size_t)gr * 128 + c];
        acc[mf][nf][reg] = v;
        s += v;
        qq += v * v;
      }
#pragma unroll
      for (int off = 1; off < 16; off <<= 1) {
        s += __shfl_xor(s, off, 64);
        qq += __shfl_xor(qq, off, 64);
      }
      if (m16 == 0) { rs[lr][wcol] = s; rq[lr][wcol] = qq; }
    }
  __syncthreads();
#pragma unroll
  for (int mf = 0; mf < 2; ++mf)
#pragma unroll
    for (int reg = 0; reg < 4; ++reg) {
      int lr = lrow0 + mf * 16 + quad * 4 + reg;
      int gr = grow0 + lr;
      float mean = (rs[lr][0] + rs[lr][1]) * (1.f / 128.f);
      float var = (rq[lr][0] + rq[lr][1]) * (1.f / 128.f) - mean * mean;
      float rstd = rsqrtf(var + EPS_);
      float sdp = 0.f;
#pragma unroll
      for (int nf = 0; nf < 4; ++nf) {
        int c = col0 + nf * 16 + m16;
        float v = (acc[mf][nf][reg] - mean) * rstd * lng[c] + lnb[c];
        C[(size_t)gr * 128 + c] = v;
        if (SDOT) sdp += v * bx[(size_t)gr * 128 + c];
      }
      if (SDOT) {
#pragma unroll
        for (int off = 1; off < 16; off <<= 1) sdp += __shfl_xor(sdp, off, 64);
        if (m16 == 0) sd[lr][wcol] = sdp;
      }
    }
  if (SDOT) {
    __syncthreads();
    if (threadIdx.x < 64) {
      int lr = threadIdx.x;
      int gr = grow0 + lr;
      float sv = sd[lr][0] + sd[lr][1];
      int t = gr & (T_ - 1);
      int bn = gr >> 7;
      int n = bn & (NA - 1);
      int b = bn >> 6;
      sdst[(size_t)b * NN + t * NA + n] = sv;
    }
  }
}

// ---------------- MFMA attention v2: K/V staged once per block in frag-linear LDS ----------------
__global__ __launch_bounds__(256) void attn_mfma(float* __restrict__ qkv) {
  const int h = blockIdx.x & (H_ - 1);
  const int bn = blockIdx.x >> 3;
  const int wave = threadIdx.x >> 6;
  const int lane = threadIdx.x & 63;
  const int m16 = lane & 15;
  const int quad = lane >> 4;
  const int row0 = wave * 32;
  const float* Qb = qkv + (size_t)bn * T_ * QLD + h * DH;
  const float* Kb = Qb + 128;
  const float* Vb = Qb + 256;
  float* Ob = (float*)Vb;

  __shared__ __bf16 Plds[4][32][136];
  __shared__ __bf16 KH[8][32][8], KL[8][32][8]; // K frag-linear: [nf][quad*16+t15][dh&7]
  __shared__ __bf16 VH[4][64][8], VL[4][64][8]; // V frag-linear: [kc][kq*16+dh][t&7]

  // cooperative stage: K and V (128 rows x 16 dh each), coalesced float4, hi/lo split
  for (int u = threadIdx.x; u < 1024; u += 256) {
    int isV = u >> 9;
    int r2 = u & 511;
    int t = r2 >> 2, c4 = r2 & 3;
    float4 v = *(const float4*)((isV ? Vb : Kb) + (size_t)t * QLD + c4 * 4);
    float xv[4] = {v.x, v.y, v.z, v.w};
#pragma unroll
    for (int i = 0; i < 4; ++i) {
      int dh = c4 * 4 + i;
      __bf16 hh = (__bf16)xv[i];
      __bf16 ll = (__bf16)(xv[i] - (float)hh);
      if (isV) {
        int kc = t >> 5, rem = t & 31;
        int vl = (rem >> 3) * 16 + dh;
        VH[kc][vl][rem & 7] = hh;
        VL[kc][vl][rem & 7] = ll;
      } else {
        int nf = t >> 4;
        int kl = (dh >> 3) * 16 + (t & 15);
        KH[nf][kl][dh & 7] = hh;
        KL[nf][kl][dh & 7] = ll;
      }
    }
  }

  // Q A-frags from global (registers, zero-pad quad>=2)
  bf16x8 qhi[2], qlo[2];
#pragma unroll
  for (int mf = 0; mf < 2; ++mf) {
    if (quad < 2) {
      split8(Qb + (size_t)(row0 + mf * 16 + m16) * QLD + quad * 8, qhi[mf], qlo[mf]);
    } else {
#pragma unroll
      for (int j = 0; j < 8; ++j) { qhi[mf][j] = (__bf16)0.f; qlo[mf][j] = (__bf16)0.f; }
    }
  }
  __syncthreads(); // staging complete

  f32x4 acc[2][8] = {};
#pragma unroll
  for (int nf = 0; nf < 8; ++nf) {
    bf16x8 khi, klo;
    if (quad < 2) {
      khi = *(const bf16x8*)&KH[nf][lane][0]; // lane in [0,32)
      klo = *(const bf16x8*)&KL[nf][lane][0];
    } else {
#pragma unroll
      for (int j = 0; j < 8; ++j) { khi[j] = (__bf16)0.f; klo[j] = (__bf16)0.f; }
    }
#pragma unroll
    for (int mf = 0; mf < 2; ++mf) {
      acc[mf][nf] = __builtin_amdgcn_mfma_f32_16x16x32_bf16(qhi[mf], khi, acc[mf][nf], 0, 0, 0);
      acc[mf][nf] = __builtin_amdgcn_mfma_f32_16x16x32_bf16(qhi[mf], klo, acc[mf][nf], 0, 0, 0);
      acc[mf][nf] = __builtin_amdgcn_mfma_f32_16x16x32_bf16(qlo[mf], khi, acc[mf][nf], 0, 0, 0);
    }
  }

  const float scale = 0.25f;
#pragma unroll
  for (int mf = 0; mf < 2; ++mf)
#pragma unroll
    for (int reg = 0; reg < 4; ++reg) {
      float mx = -1e30f;
#pragma unroll
      for (int nf = 0; nf < 8; ++nf) mx = fmaxf(mx, acc[mf][nf][reg]);
#pragma unroll
      for (int off = 1; off < 16; off <<= 1) mx = fmaxf(mx, __shfl_xor(mx, off, 64));
      float sum = 0.f;
#pragma unroll
      for (int nf = 0; nf < 8; ++nf) {
        float e = __expf((acc[mf][nf][reg] - mx) * scale);
        acc[mf][nf][reg] = e;
        sum += e;
      }
#pragma unroll
      for (int off = 1; off < 16; off <<= 1) sum += __shfl_xor(sum, off, 64);
      float inv = 1.f / sum;
#pragma unroll
      for (int nf = 0; nf < 8; ++nf) acc[mf][nf][reg] *= inv;
    }

#pragma unroll
  for (int mf = 0; mf < 2; ++mf)
#pragma unroll
    for (int nf = 0; nf < 8; ++nf)
#pragma unroll
      for (int reg = 0; reg < 4; ++reg)
        Plds[wave][mf * 16 + quad * 4 + reg][nf * 16 + m16] = (__bf16)acc[mf][nf][reg];

  f32x4 oacc[2] = {};
#pragma unroll
  for (int kc = 0; kc < 4; ++kc) {
    bf16x8 pa0 = *(const bf16x8*)&Plds[wave][m16][kc * 32 + quad * 8];
    bf16x8 pa1 = *(const bf16x8*)&Plds[wave][16 + m16][kc * 32 + quad * 8];
    bf16x8 vhi = *(const bf16x8*)&VH[kc][lane][0];
    bf16x8 vlo = *(const bf16x8*)&VL[kc][lane][0];
    oacc[0] = __builtin_amdgcn_mfma_f32_16x16x32_bf16(pa0, vhi, oacc[0], 0, 0, 0);
    oacc[0] = __builtin_amdgcn_mfma_f32_16x16x32_bf16(pa0, vlo, oacc[0], 0, 0, 0);
    oacc[1] = __builtin_amdgcn_mfma_f32_16x16x32_bf16(pa1, vhi, oacc[1], 0, 0, 0);
    oacc[1] = __builtin_amdgcn_mfma_f32_16x16x32_bf16(pa1, vlo, oacc[1], 0, 0, 0);
  }

  // Global V slice was consumed during staging (before the barrier) — O write is safe.
#pragma unroll
  for (int mf = 0; mf < 2; ++mf)
#pragma unroll
    for (int reg = 0; reg < 4; ++reg) {
      int r = row0 + mf * 16 + quad * 4 + reg;
      Ob[(size_t)r * QLD + m16] = oacc[mf][reg];
    }
}

// ---------------- edge scatter ----------------
__global__ __launch_bounds__(256) void scatter_kernel(
    const float* __restrict__ s, const int* __restrict__ ei,
    const float* __restrict__ ew, float* __restrict__ g) {
  int idx = blockIdx.x * 256 + threadIdx.x;
  if (idx >= B_ * E_) return;
  int b = idx >> 16;
  int e = idx & (E_ - 1);
  int src = ei[(size_t)b * 2 * E_ + e];
  int dst = ei[(size_t)b * 2 * E_ + E_ + e];
  float w = ew[(size_t)b * E_ + e];
  atomicAdd(&g[(size_t)b * NN + dst], w * s[(size_t)b * NN + src]);
}

// ---------------- partial sums for global mean/var ----------------
__global__ __launch_bounds__(256) void stats_partial(
    const float* __restrict__ g, float* __restrict__ st) {
  int i = blockIdx.x * 256 + threadIdx.x;
  float v = g[i];
  float sum = v, sq = v * v;
#pragma unroll
  for (int off = 32; off; off >>= 1) {
    sum += __shfl_down(sum, off, 64);
    sq += __shfl_down(sq, off, 64);
  }
  __shared__ float s1[4], s2[4];
  int w = threadIdx.x >> 6;
  if ((threadIdx.x & 63) == 0) { s1[w] = sum; s2[w] = sq; }
  __syncthreads();
  if (threadIdx.x == 0) {
    atomicAdd(&st[0], s1[0] + s1[1] + s1[2] + s1[3]);
    atomicAdd(&st[1], s2[0] + s2[1] + s2[2] + s2[3]);
  }
}

// ---------------- final (fp32 out) ----------------
__global__ __launch_bounds__(256) void final_kernel(
    const float* __restrict__ g, const float* __restrict__ st,
    const float* __restrict__ bng, const float* __restrict__ bnb,
    const float* __restrict__ lw, const float* __restrict__ lb,
    float* __restrict__ out) {
  int idx = blockIdx.x * 256 + threadIdx.x;
  if (idx >= NTOT * D_) return;
  int d = idx & (D_ - 1);
  int r = idx >> 7;
  int t = r & (T_ - 1);
  int bn = r >> 7;
  int n = bn & (NA - 1);
  int b = bn >> 6;
  const float invn = 1.f / (float)(B_ * NN);
  float m = st[0] * invn;
  float var = st[1] * invn - m * m;
  float rs = rsqrtf(var + EPS_);
  float gv = g[(size_t)b * NN + t * NA + n];
  float val = (gv - m) * rs * bng[0] + bnb[0];
  out[idx] = val * lw[d] + lb[d];
}

extern "C" void kernel_launch(void* const* d_in, const int* in_sizes, int n_in,
                              void* d_out, int out_size, void* d_ws, size_t ws_size,
                              hipStream_t stream) {
  const float* hist = (const float*)d_in[0];
  const int* eidx = (const int*)d_in[1];
  const float* ew = (const float*)d_in[2];
  const float* hw = (const float*)d_in[3];
  const float* hb = (const float*)d_in[4];
  const float* wq = (const float*)d_in[5];
  const float* bq = (const float*)d_in[6];
  const float* wk = (const float*)d_in[7];
  const float* bk = (const float*)d_in[8];
  const float* wv = (const float*)d_in[9];
  const float* bv = (const float*)d_in[10];
  const float* wo = (const float*)d_in[11];
  const float* bo = (const float*)d_in[12];
  const float* ln1g = (const float*)d_in[13];
  const float* ln1b = (const float*)d_in[14];
  const float* w1 = (const float*)d_in[15];
  const float* b1 = (const float*)d_in[16];
  const float* w2 = (const float*)d_in[17];
  const float* b2 = (const float*)d_in[18];
  const float* ln2g = (const float*)d_in[19];
  const float* ln2b = (const float*)d_in[20];
  const float* bng = (const float*)d_in[21];
  const float* bnb = (const float*)d_in[22];
  const float* lgw = (const float*)d_in[23];
  const float* lgb = (const float*)d_in[24];
  float* out = (float*)d_out;

  float* ws = (float*)d_ws;
  const size_t NE = NE_;
  float* bx = ws + 0 * NE;
  float* be = ws + 1 * NE;
  float* h1 = ws + 2 * NE;
  float* qkv = ws + 3 * NE;   // 3NE, [row][384]
  float* ffmid = ws + 3 * NE; // 4NE, overlaps dead qkv
  float* bs_ = ws + 7 * NE;
  float* bg_ = bs_ + NTOT;
  float* bst = bg_ + NTOT;
  float* pbias = bst + 2;
  const int LW = 196608;
  __bf16* whiB = (__bf16*)(pbias + L_ * QLD);
  __bf16* wloB = whiB + (size_t)L_ * LW;

  convert_weights<<<(L_ * LW + 255) / 256, 256, 0, stream>>>(
      wq, wk, wv, wo, w1, w2, whiB, wloB);
  bias_pack<<<(L_ * QLD + 255) / 256, 256, 0, stream>>>(bq, bk, bv, pbias);
  embed_kernel<<<(NTOT * D_) / 256, 256, 0, stream>>>(hist, hw, hb, bx, be);

  for (int l = 0; l < L_; ++l) {
    const __bf16* hiL = whiB + (size_t)l * LW;
    const __bf16* loL = wloB + (size_t)l * LW;
    gemm_small<0, 128><<<dim3(3, NTOT / 64), 256, 0, stream>>>(
        be, 128, hiL, loL, pbias + l * QLD, qkv, QLD);
    attn_mfma<<<B_ * NA * H_, 256, 0, stream>>>(qkv);
    gemm_ln<128><<<dim3(1, NTOT / 64), 256, 0, stream>>>(
        qkv + 256, QLD, hiL + 49152, loL + 49152, bo + l * D_, be,
        ln1g + l * D_, ln1b + l * D_, h1);
    gemm_small<1, 128><<<dim3(4, NTOT / 64), 256, 0, stream>>>(
        h1, 128, hiL + 65536, loL + 65536, b1 + l * DFF, ffmid, 512);
    if (l < L_ - 1) {
      ff2_ln<0><<<dim3(1, NTOT / 64), 256, 0, stream>>>(
          ffmid, hiL + 131072, loL + 131072, b2 + l * D_, h1,
          ln2g + l * D_, ln2b + l * D_, be, nullptr, nullptr);
    } else {
      ff2_ln<1><<<dim3(1, NTOT / 64), 256, 0, stream>>>(
          ffmid, hiL + 131072, loL + 131072, b2 + l * D_, h1,
          ln2g + l * D_, ln2b + l * D_, be, bx, bs_);
    }
  }

  hipMemsetAsync(bg_, 0, ((size_t)B_ * NN + 2) * sizeof(float), stream);
  scatter_kernel<<<(B_ * E_) / 256, 256, 0, stream>>>(bs_, eidx, ew, bg_);
  stats_partial<<<(B_ * NN) / 256, 256, 0, stream>>>(bg_, bst);
  final_kernel<<<(NTOT * D_) / 256, 256, 0, stream>>>(bg_, bst, bng, bnb, lgw, lgb, out);
}

// Round 9
// 505.045 us; speedup vs baseline: 1.2088x; 1.0983x over previous
//
#include <hip/hip_runtime.h>
#include <hip/hip_bf16.h>
#include <math.h>

#define EPS_ 1e-5f
constexpr int B_ = 4, NA = 64, T_ = 128, D_ = 128, H_ = 8, L_ = 3, DFF = 512, E_ = 65536;
constexpr int DH = D_ / H_;        // 16
constexpr int NN = T_ * NA;        // 8192
constexpr int NTOT = B_ * NA * T_; // 32768
constexpr int QLD = 384;           // packed QKV bias stride
constexpr size_t NE_ = (size_t)NTOT * D_;

typedef __bf16 bf16x8 __attribute__((ext_vector_type(8)));
typedef float f32x4 __attribute__((ext_vector_type(4)));

// ---------------- embed: x = hist@W + b ; e = x + posenc ----------------
__global__ __launch_bounds__(256) void embed_kernel(
    const float* __restrict__ hist, const float* __restrict__ w,
    const float* __restrict__ b, float* __restrict__ x, float* __restrict__ e) {
  int idx = blockIdx.x * 256 + threadIdx.x;
  if (idx >= NTOT * D_) return;
  int d = idx & (D_ - 1);
  int r = idx >> 7;
  int t = r & (T_ - 1);
  const float* hp = hist + (size_t)r * 3;
  float acc = b[d];
  acc += hp[0] * w[0 * D_ + d];
  acc += hp[1] * w[1 * D_ + d];
  acc += hp[2] * w[2 * D_ + d];
  x[idx] = acc;
  int p = d >> 1;
  float ang = (float)t * expf(-logf(10000.f) * (2.f * (float)p) / (float)D_);
  float pe = (d & 1) ? cosf(ang) : sinf(ang);
  e[idx] = acc + pe;
}

// ---------------- weight split into FRAGMENT-LINEAR bf16 hi/lo ----------------
__global__ __launch_bounds__(256) void convert_weights(
    const float* __restrict__ wq, const float* __restrict__ wk,
    const float* __restrict__ wv, const float* __restrict__ wo,
    const float* __restrict__ w1, const float* __restrict__ w2,
    __bf16* __restrict__ hi, __bf16* __restrict__ lo) {
  const int LW = 196608;
  int idx = blockIdx.x * 256 + threadIdx.x;
  if (idx >= L_ * LW) return;
  int l = idx / LW;
  int rem = idx - l * LW;
  float src;
  int n, k, K, segoff;
  if (rem < 49152) { // qkv
    n = rem >> 7; k = rem & 127; K = 128; segoff = 0;
    int which = n >> 7, nl = n & 127;
    const float* W = (which == 0) ? wq : (which == 1) ? wk : wv;
    src = W[(size_t)l * 16384 + k * 128 + nl];
  } else if (rem < 65536) { // wo
    int r2 = rem - 49152;
    n = r2 >> 7; k = r2 & 127; K = 128; segoff = 49152;
    src = wo[(size_t)l * 16384 + k * 128 + n];
  } else if (rem < 131072) { // w1
    int r2 = rem - 65536;
    n = r2 >> 7; k = r2 & 127; K = 128; segoff = 65536;
    src = w1[(size_t)l * 65536 + k * 512 + n];
  } else { // w2
    int r2 = rem - 131072;
    n = r2 >> 9; k = r2 & 511; K = 512; segoff = 131072;
    src = w2[(size_t)l * 65536 + k * 128 + n];
  }
  int nt = n >> 4, kt = k >> 5;
  int lane = ((k >> 3) & 3) * 16 + (n & 15);
  int j = k & 7;
  int dst = l * LW + segoff + ((nt * (K / 32) + kt) * 64 + lane) * 8 + j;
  __bf16 h = (__bf16)src;
  hi[dst] = h;
  lo[dst] = (__bf16)(src - (float)h);
}

// ---------------- pack QKV biases ----------------
__global__ __launch_bounds__(256) void bias_pack(
    const float* __restrict__ bq, const float* __restrict__ bk,
    const float* __restrict__ bv, float* __restrict__ pb) {
  int idx = blockIdx.x * 256 + threadIdx.x;
  if (idx >= L_ * QLD) return;
  int l = idx / QLD, n = idx - l * QLD;
  int which = n >> 7, nl = n & 127;
  const float* src = (which == 0) ? bq : (which == 1) ? bk : bv;
  pb[idx] = src[l * 128 + nl];
}

__device__ __forceinline__ void split8(const float* __restrict__ p,
                                       bf16x8& hi, bf16x8& lo) {
  float4 x0 = *(const float4*)p;
  float4 x1 = *(const float4*)(p + 4);
  float xv[8] = {x0.x, x0.y, x0.z, x0.w, x1.x, x1.y, x1.z, x1.w};
#pragma unroll
  for (int j = 0; j < 8; ++j) {
    __bf16 h = (__bf16)xv[j];
    hi[j] = h;
    lo[j] = (__bf16)(xv[j] - (float)h);
  }
}

// ---------------- MFMA GEMM, 128x128 tile (wave 64x64), frag-linear W [r12, r0-proven] ----------------
template <int EPI, int K>
__global__ __launch_bounds__(256) void gemm_big(
    const float* __restrict__ A, int lda,
    const __bf16* __restrict__ Whi, const __bf16* __restrict__ Wlo,
    const float* __restrict__ bias,
    float* __restrict__ C, int ldc) {
  const int wave = threadIdx.x >> 6;
  const int lane = threadIdx.x & 63;
  const int m16 = lane & 15;
  const int quad = lane >> 4;
  const int wrow = wave >> 1, wcol = wave & 1;
  const int row0 = blockIdx.y * 128 + wrow * 64;
  const int col0 = blockIdx.x * 128 + wcol * 64;
  const int ctb = col0 >> 4;

  f32x4 acc[4][4] = {};
#pragma unroll
  for (int k0 = 0; k0 < K; k0 += 32) {
    bf16x8 ahi[4], alo[4];
#pragma unroll
    for (int mf = 0; mf < 4; ++mf)
      split8(A + (size_t)(row0 + mf * 16 + m16) * lda + k0 + quad * 8, ahi[mf], alo[mf]);
    bf16x8 bhi[4], blo[4];
#pragma unroll
    for (int nf = 0; nf < 4; ++nf) {
      size_t off = ((size_t)(ctb + nf) * (K / 32) + (k0 >> 5)) * 512 + lane * 8;
      bhi[nf] = *(const bf16x8*)(Whi + off);
      blo[nf] = *(const bf16x8*)(Wlo + off);
    }
#pragma unroll
    for (int mf = 0; mf < 4; ++mf)
#pragma unroll
      for (int nf = 0; nf < 4; ++nf) {
        acc[mf][nf] = __builtin_amdgcn_mfma_f32_16x16x32_bf16(ahi[mf], bhi[nf], acc[mf][nf], 0, 0, 0);
        acc[mf][nf] = __builtin_amdgcn_mfma_f32_16x16x32_bf16(ahi[mf], blo[nf], acc[mf][nf], 0, 0, 0);
        acc[mf][nf] = __builtin_amdgcn_mfma_f32_16x16x32_bf16(alo[mf], bhi[nf], acc[mf][nf], 0, 0, 0);
      }
  }
#pragma unroll
  for (int mf = 0; mf < 4; ++mf)
#pragma unroll
    for (int nf = 0; nf < 4; ++nf) {
      int c = col0 + nf * 16 + m16;
      float bj = bias[c];
#pragma unroll
      for (int reg = 0; reg < 4; ++reg) {
        int r = row0 + mf * 16 + quad * 4 + reg;
        float v = acc[mf][nf][reg] + bj;
        if (EPI == 1) v = fmaxf(v, 0.f);
        C[(size_t)r * ldc + c] = v;
      }
    }
}

// ---------------- GEMM + bias + resid + LayerNorm; block 64x128, register A [r12] ----------------
template <int K>
__global__ __launch_bounds__(256) void gemm_ln(
    const float* __restrict__ A, int lda,
    const __bf16* __restrict__ Whi, const __bf16* __restrict__ Wlo,
    const float* __restrict__ bias, const float* __restrict__ resid,
    const float* __restrict__ lng, const float* __restrict__ lnb,
    float* __restrict__ C) {
  const int wave = threadIdx.x >> 6;
  const int lane = threadIdx.x & 63;
  const int m16 = lane & 15;
  const int quad = lane >> 4;
  const int wrow = wave >> 1, wcol = wave & 1;
  const int row0 = blockIdx.y * 64 + wrow * 32;
  const int col0 = wcol * 64;
  const int ctb = wcol * 4;

  f32x4 acc[2][4] = {};
#pragma unroll
  for (int k0 = 0; k0 < K; k0 += 32) {
    bf16x8 ahi[2], alo[2];
#pragma unroll
    for (int mf = 0; mf < 2; ++mf)
      split8(A + (size_t)(row0 + mf * 16 + m16) * lda + k0 + quad * 8, ahi[mf], alo[mf]);
    bf16x8 bhi[4], blo[4];
#pragma unroll
    for (int nf = 0; nf < 4; ++nf) {
      size_t off = ((size_t)(ctb + nf) * (K / 32) + (k0 >> 5)) * 512 + lane * 8;
      bhi[nf] = *(const bf16x8*)(Whi + off);
      blo[nf] = *(const bf16x8*)(Wlo + off);
    }
#pragma unroll
    for (int mf = 0; mf < 2; ++mf)
#pragma unroll
      for (int nf = 0; nf < 4; ++nf) {
        acc[mf][nf] = __builtin_amdgcn_mfma_f32_16x16x32_bf16(ahi[mf], bhi[nf], acc[mf][nf], 0, 0, 0);
        acc[mf][nf] = __builtin_amdgcn_mfma_f32_16x16x32_bf16(ahi[mf], blo[nf], acc[mf][nf], 0, 0, 0);
        acc[mf][nf] = __builtin_amdgcn_mfma_f32_16x16x32_bf16(alo[mf], bhi[nf], acc[mf][nf], 0, 0, 0);
      }
  }
  __shared__ float rs[64][2], rq[64][2];
#pragma unroll
  for (int mf = 0; mf < 2; ++mf)
#pragma unroll
    for (int reg = 0; reg < 4; ++reg) {
      int lr = wrow * 32 + mf * 16 + quad * 4 + reg;
      int gr = blockIdx.y * 64 + lr;
      float s = 0.f, qq = 0.f;
#pragma unroll
      for (int nf = 0; nf < 4; ++nf) {
        int c = col0 + nf * 16 + m16;
        float v = acc[mf][nf][reg] + bias[c] + resid[(size_t)gr * 128 + c];
        acc[mf][nf][reg] = v;
        s += v;
        qq += v * v;
      }
#pragma unroll
      for (int off = 1; off < 16; off <<= 1) {
        s += __shfl_xor(s, off, 64);
        qq += __shfl_xor(qq, off, 64);
      }
      if (m16 == 0) { rs[lr][wcol] = s; rq[lr][wcol] = qq; }
    }
  __syncthreads();
#pragma unroll
  for (int mf = 0; mf < 2; ++mf)
#pragma unroll
    for (int reg = 0; reg < 4; ++reg) {
      int lr = wrow * 32 + mf * 16 + quad * 4 + reg;
      int gr = blockIdx.y * 64 + lr;
      float mean = (rs[lr][0] + rs[lr][1]) * (1.f / 128.f);
      float var = (rq[lr][0] + rq[lr][1]) * (1.f / 128.f) - mean * mean;
      float rstd = rsqrtf(var + EPS_);
#pragma unroll
      for (int nf = 0; nf < 4; ++nf) {
        int c = col0 + nf * 16 + m16;
        C[(size_t)gr * 128 + c] = (acc[mf][nf][reg] - mean) * rstd * lng[c] + lnb[c];
      }
    }
}

// ---------------- FF2 + LN (staged A, K=512) [r12]; SDOT fuses gating dot [r15] ----------------
template <int SDOT>
__global__ __launch_bounds__(256) void ff2_ln(
    const float* __restrict__ A, // ffmid [M][512]
    const __bf16* __restrict__ Whi, const __bf16* __restrict__ Wlo,
    const float* __restrict__ bias, const float* __restrict__ resid,
    const float* __restrict__ lng, const float* __restrict__ lnb,
    float* __restrict__ C,
    const float* __restrict__ bx, float* __restrict__ sdst) {
  const int wave = threadIdx.x >> 6;
  const int lane = threadIdx.x & 63;
  const int m16 = lane & 15;
  const int quad = lane >> 4;
  const int wrow = wave >> 1, wcol = wave & 1;
  const int grow0 = blockIdx.y * 64;
  const int lrow0 = wrow * 32;
  const int col0 = wcol * 64;
  const int ctb = wcol * 4;

  __shared__ float As[64][129];

  f32x4 acc[2][4] = {};
  for (int kc = 0; kc < 4; ++kc) {
    if (kc) __syncthreads();
#pragma unroll
    for (int u = 0; u < 8; ++u) {
      int unit = threadIdx.x + u * 256;
      int r = unit >> 5, c4 = unit & 31;
      float4 v = *(const float4*)(A + (size_t)(grow0 + r) * 512 + kc * 128 + c4 * 4);
      As[r][c4 * 4 + 0] = v.x;
      As[r][c4 * 4 + 1] = v.y;
      As[r][c4 * 4 + 2] = v.z;
      As[r][c4 * 4 + 3] = v.w;
    }
    __syncthreads();
#pragma unroll
    for (int kt = 0; kt < 4; ++kt) {
      bf16x8 ahi[2], alo[2];
#pragma unroll
      for (int mf = 0; mf < 2; ++mf)
        split8(&As[lrow0 + mf * 16 + m16][kt * 32 + quad * 8], ahi[mf], alo[mf]);
      bf16x8 bhi[4], blo[4];
#pragma unroll
      for (int nf = 0; nf < 4; ++nf) {
        size_t off = ((size_t)(ctb + nf) * 16 + (kc * 4 + kt)) * 512 + lane * 8;
        bhi[nf] = *(const bf16x8*)(Whi + off);
        blo[nf] = *(const bf16x8*)(Wlo + off);
      }
#pragma unroll
      for (int mf = 0; mf < 2; ++mf)
#pragma unroll
        for (int nf = 0; nf < 4; ++nf) {
          acc[mf][nf] = __builtin_amdgcn_mfma_f32_16x16x32_bf16(ahi[mf], bhi[nf], acc[mf][nf], 0, 0, 0);
          acc[mf][nf] = __builtin_amdgcn_mfma_f32_16x16x32_bf16(ahi[mf], blo[nf], acc[mf][nf], 0, 0, 0);
          acc[mf][nf] = __builtin_amdgcn_mfma_f32_16x16x32_bf16(alo[mf], bhi[nf], acc[mf][nf], 0, 0, 0);
        }
    }
  }
  __shared__ float rs[64][2], rq[64][2];
  __shared__ float sd[64][2];
#pragma unroll
  for (int mf = 0; mf < 2; ++mf)
#pragma unroll
    for (int reg = 0; reg < 4; ++reg) {
      int lr = lrow0 + mf * 16 + quad * 4 + reg;
      int gr = grow0 + lr;
      float s = 0.f, qq = 0.f;
#pragma unroll
      for (int nf = 0; nf < 4; ++nf) {
        int c = col0 + nf * 16 + m16;
        float v = acc[mf][nf][reg] + bias[c] + resid[(size_t)gr * 128 + c];
        acc[mf][nf][reg] = v;
        s += v;
        qq += v * v;
      }
#pragma unroll
      for (int off = 1; off < 16; off <<= 1) {
        s += __shfl_xor(s, off, 64);
        qq += __shfl_xor(qq, off, 64);
      }
      if (m16 == 0) { rs[lr][wcol] = s; rq[lr][wcol] = qq; }
    }
  __syncthreads();
#pragma unroll
  for (int mf = 0; mf < 2; ++mf)
#pragma unroll
    for (int reg = 0; reg < 4; ++reg) {
      int lr = lrow0 + mf * 16 + quad * 4 + reg;
      int gr = grow0 + lr;
      float mean = (rs[lr][0] + rs[lr][1]) * (1.f / 128.f);
      float var = (rq[lr][0] + rq[lr][1]) * (1.f / 128.f) - mean * mean;
      float rstd = rsqrtf(var + EPS_);
      float sdp = 0.f;
#pragma unroll
      for (int nf = 0; nf < 4; ++nf) {
        int c = col0 + nf * 16 + m16;
        float v = (acc[mf][nf][reg] - mean) * rstd * lng[c] + lnb[c];
        C[(size_t)gr * 128 + c] = v;
        if (SDOT) sdp += v * bx[(size_t)gr * 128 + c];
      }
      if (SDOT) {
#pragma unroll
        for (int off = 1; off < 16; off <<= 1) sdp += __shfl_xor(sdp, off, 64);
        if (m16 == 0) sd[lr][wcol] = sdp;
      }
    }
  if (SDOT) {
    __syncthreads();
    if (threadIdx.x < 64) {
      int lr = threadIdx.x;
      int gr = grow0 + lr;
      float sv = sd[lr][0] + sd[lr][1];
      int t = gr & (T_ - 1);
      int bn = gr >> 7;
      int n = bn & (NA - 1);
      int b = bn >> 6;
      sdst[(size_t)b * NN + t * NA + n] = sv;
    }
  }
}

// ---------------- FUSED QKV-GEMM + attention [r23] ----------------
// Each block (bn,h) computes its OWN Q,K,V slice (128 rows x 16 dims each) via a mini-GEMM
// (disjoint column slices across heads -> zero MFMA redundancy vs the deleted QKV dispatch),
// stages K/V to shared LDS and Q to a wave-private region aliased into Plds[wave] (Q is
// consumed into registers before the P-write clobbers it), then runs the r0-proven attention.
// Removes: the per-layer QKV GEMM dispatch + the 48MB qkv write + 48MB re-read. Adds: 8x
// redundant A-tile reads (64KB/block, L2-resident). Mini-GEMM accumulation order, bias-add,
// and hi/lo split are bitwise-identical to the old gemm_big->memory->split8 path.
__global__ __launch_bounds__(256) void attn_fused(
    const float* __restrict__ A,       // be [NTOT][128]
    const __bf16* __restrict__ Whi, const __bf16* __restrict__ Wlo, // layer qkv segment
    const float* __restrict__ pb,      // packed qkv bias [384]
    float* __restrict__ O) {           // [NTOT][128]
  const int h = blockIdx.x & (H_ - 1);
  const int bn = blockIdx.x >> 3;
  const int wave = threadIdx.x >> 6;
  const int lane = threadIdx.x & 63;
  const int m16 = lane & 15;
  const int quad = lane >> 4;
  const int row0 = wave * 32;
  const float* Ab = A + (size_t)bn * T_ * 128;

  __shared__ __bf16 Plds[4][32][136];
  __shared__ __bf16 KH[8][32][8], KL[8][32][8]; // K frag-linear: [t>>4][(dh>>3)*16+t15][dh&7]
  __shared__ __bf16 VH[4][64][8], VL[4][64][8]; // V frag-linear: [t>>5][(rem>>3)*16+dh][rem&7]
  __bf16* QHw = &Plds[wave][0][0];              // wave-private Q: [2][32][8] (aliased)
  __bf16* QLw = QHw + 512;

  // ---- mini-GEMM: rows [row0, row0+32) x {Q,K,V} cols [h*16, h*16+16)
  f32x4 qkv[2][3] = {}; // [mf][seg]
#pragma unroll
  for (int k0 = 0; k0 < 128; k0 += 32) {
    bf16x8 ahi[2], alo[2];
#pragma unroll
    for (int mf = 0; mf < 2; ++mf)
      split8(Ab + (size_t)(row0 + mf * 16 + m16) * 128 + k0 + quad * 8, ahi[mf], alo[mf]);
    bf16x8 bhi[3], blo[3];
#pragma unroll
    for (int s = 0; s < 3; ++s) {
      size_t off = ((size_t)(s * 8 + h) * 4 + (k0 >> 5)) * 512 + lane * 8; // ctb = s*8+h
      bhi[s] = *(const bf16x8*)(Whi + off);
      blo[s] = *(const bf16x8*)(Wlo + off);
    }
#pragma unroll
    for (int mf = 0; mf < 2; ++mf)
#pragma unroll
      for (int s = 0; s < 3; ++s) {
        qkv[mf][s] = __builtin_amdgcn_mfma_f32_16x16x32_bf16(ahi[mf], bhi[s], qkv[mf][s], 0, 0, 0);
        qkv[mf][s] = __builtin_amdgcn_mfma_f32_16x16x32_bf16(ahi[mf], blo[s], qkv[mf][s], 0, 0, 0);
        qkv[mf][s] = __builtin_amdgcn_mfma_f32_16x16x32_bf16(alo[mf], bhi[s], qkv[mf][s], 0, 0, 0);
      }
  }

  // ---- stage from registers: C/D layout => lane holds OUT[row=mf*16+quad*4+reg][col=m16]
#pragma unroll
  for (int mf = 0; mf < 2; ++mf)
#pragma unroll
    for (int reg = 0; reg < 4; ++reg) {
      const int tl = mf * 16 + quad * 4 + reg; // local row 0..31
      const int t = row0 + tl;                 // block row 0..127
      const int dh = m16;
      { // Q -> wave-private
        float v = qkv[mf][0][reg] + pb[h * 16 + dh];
        __bf16 hh = (__bf16)v;
        __bf16 ll = (__bf16)(v - (float)hh);
        int idx = mf * 256 + ((dh >> 3) * 16 + (tl & 15)) * 8 + (dh & 7);
        QHw[idx] = hh;
        QLw[idx] = ll;
      }
      { // K -> shared
        float v = qkv[mf][1][reg] + pb[128 + h * 16 + dh];
        __bf16 hh = (__bf16)v;
        __bf16 ll = (__bf16)(v - (float)hh);
        KH[t >> 4][(dh >> 3) * 16 + (t & 15)][dh & 7] = hh;
        KL[t >> 4][(dh >> 3) * 16 + (t & 15)][dh & 7] = ll;
      }
      { // V -> shared
        float v = qkv[mf][2][reg] + pb[256 + h * 16 + dh];
        __bf16 hh = (__bf16)v;
        __bf16 ll = (__bf16)(v - (float)hh);
        int kc = t >> 5, rem = t & 31;
        int vl = (rem >> 3) * 16 + dh;
        VH[kc][vl][rem & 7] = hh;
        VL[kc][vl][rem & 7] = ll;
      }
    }

  // ---- read own Q A-frags back (wave-private; same-wave LDS dependency)
  bf16x8 qhi[2], qlo[2];
#pragma unroll
  for (int mf = 0; mf < 2; ++mf) {
    if (quad < 2) {
      int idx = mf * 256 + (quad * 16 + m16) * 8;
      qhi[mf] = *(const bf16x8*)&QHw[idx];
      qlo[mf] = *(const bf16x8*)&QLw[idx];
    } else {
#pragma unroll
      for (int j = 0; j < 8; ++j) { qhi[mf][j] = (__bf16)0.f; qlo[mf][j] = (__bf16)0.f; }
    }
  }
  __syncthreads(); // K/V staging visible to all waves

  f32x4 acc[2][8] = {};
#pragma unroll
  for (int nf = 0; nf < 8; ++nf) {
    bf16x8 khi, klo;
    if (quad < 2) {
      khi = *(const bf16x8*)&KH[nf][lane][0]; // lane in [0,32)
      klo = *(const bf16x8*)&KL[nf][lane][0];
    } else {
#pragma unroll
      for (int j = 0; j < 8; ++j) { khi[j] = (__bf16)0.f; klo[j] = (__bf16)0.f; }
    }
#pragma unroll
    for (int mf = 0; mf < 2; ++mf) {
      acc[mf][nf] = __builtin_amdgcn_mfma_f32_16x16x32_bf16(qhi[mf], khi, acc[mf][nf], 0, 0, 0);
      acc[mf][nf] = __builtin_amdgcn_mfma_f32_16x16x32_bf16(qhi[mf], klo, acc[mf][nf], 0, 0, 0);
      acc[mf][nf] = __builtin_amdgcn_mfma_f32_16x16x32_bf16(qlo[mf], khi, acc[mf][nf], 0, 0, 0);
    }
  }

  const float scale = 0.25f;
#pragma unroll
  for (int mf = 0; mf < 2; ++mf)
#pragma unroll
    for (int reg = 0; reg < 4; ++reg) {
      float mx = -1e30f;
#pragma unroll
      for (int nf = 0; nf < 8; ++nf) mx = fmaxf(mx, acc[mf][nf][reg]);
#pragma unroll
      for (int off = 1; off < 16; off <<= 1) mx = fmaxf(mx, __shfl_xor(mx, off, 64));
      float sum = 0.f;
#pragma unroll
      for (int nf = 0; nf < 8; ++nf) {
        float e = __expf((acc[mf][nf][reg] - mx) * scale);
        acc[mf][nf][reg] = e;
        sum += e;
      }
#pragma unroll
      for (int off = 1; off < 16; off <<= 1) sum += __shfl_xor(sum, off, 64);
      float inv = 1.f / sum;
#pragma unroll
      for (int nf = 0; nf < 8; ++nf) acc[mf][nf][reg] *= inv;
    }

#pragma unroll
  for (int mf = 0; mf < 2; ++mf)
#pragma unroll
    for (int nf = 0; nf < 8; ++nf)
#pragma unroll
      for (int reg = 0; reg < 4; ++reg)
        Plds[wave][mf * 16 + quad * 4 + reg][nf * 16 + m16] = (__bf16)acc[mf][nf][reg];

  f32x4 oacc[2] = {};
#pragma unroll
  for (int kc = 0; kc < 4; ++kc) {
    bf16x8 pa0 = *(const bf16x8*)&Plds[wave][m16][kc * 32 + quad * 8];
    bf16x8 pa1 = *(const bf16x8*)&Plds[wave][16 + m16][kc * 32 + quad * 8];
    bf16x8 vhi = *(const bf16x8*)&VH[kc][lane][0];
    bf16x8 vlo = *(const bf16x8*)&VL[kc][lane][0];
    oacc[0] = __builtin_amdgcn_mfma_f32_16x16x32_bf16(pa0, vhi, oacc[0], 0, 0, 0);
    oacc[0] = __builtin_amdgcn_mfma_f32_16x16x32_bf16(pa0, vlo, oacc[0], 0, 0, 0);
    oacc[1] = __builtin_amdgcn_mfma_f32_16x16x32_bf16(pa1, vhi, oacc[1], 0, 0, 0);
    oacc[1] = __builtin_amdgcn_mfma_f32_16x16x32_bf16(pa1, vlo, oacc[1], 0, 0, 0);
  }

#pragma unroll
  for (int mf = 0; mf < 2; ++mf)
#pragma unroll
    for (int reg = 0; reg < 4; ++reg) {
      int r = row0 + mf * 16 + quad * 4 + reg;
      O[((size_t)bn * T_ + r) * 128 + h * 16 + m16] = oacc[mf][reg];
    }
}

// ---------------- edge scatter ----------------
__global__ __launch_bounds__(256) void scatter_kernel(
    const float* __restrict__ s, const int* __restrict__ ei,
    const float* __restrict__ ew, float* __restrict__ g) {
  int idx = blockIdx.x * 256 + threadIdx.x;
  if (idx >= B_ * E_) return;
  int b = idx >> 16;
  int e = idx & (E_ - 1);
  int src = ei[(size_t)b * 2 * E_ + e];
  int dst = ei[(size_t)b * 2 * E_ + E_ + e];
  float w = ew[(size_t)b * E_ + e];
  atomicAdd(&g[(size_t)b * NN + dst], w * s[(size_t)b * NN + src]);
}

// ---------------- partial sums for global mean/var ----------------
__global__ __launch_bounds__(256) void stats_partial(
    const float* __restrict__ g, float* __restrict__ st) {
  int i = blockIdx.x * 256 + threadIdx.x;
  float v = g[i];
  float sum = v, sq = v * v;
#pragma unroll
  for (int off = 32; off; off >>= 1) {
    sum += __shfl_down(sum, off, 64);
    sq += __shfl_down(sq, off, 64);
  }
  __shared__ float s1[4], s2[4];
  int w = threadIdx.x >> 6;
  if ((threadIdx.x & 63) == 0) { s1[w] = sum; s2[w] = sq; }
  __syncthreads();
  if (threadIdx.x == 0) {
    atomicAdd(&st[0], s1[0] + s1[1] + s1[2] + s1[3]);
    atomicAdd(&st[1], s2[0] + s2[1] + s2[2] + s2[3]);
  }
}

// ---------------- final (fp32 out) ----------------
__global__ __launch_bounds__(256) void final_kernel(
    const float* __restrict__ g, const float* __restrict__ st,
    const float* __restrict__ bng, const float* __restrict__ bnb,
    const float* __restrict__ lw, const float* __restrict__ lb,
    float* __restrict__ out) {
  int idx = blockIdx.x * 256 + threadIdx.x;
  if (idx >= NTOT * D_) return;
  int d = idx & (D_ - 1);
  int r = idx >> 7;
  int t = r & (T_ - 1);
  int bn = r >> 7;
  int n = bn & (NA - 1);
  int b = bn >> 6;
  const float invn = 1.f / (float)(B_ * NN);
  float m = st[0] * invn;
  float var = st[1] * invn - m * m;
  float rs = rsqrtf(var + EPS_);
  float gv = g[(size_t)b * NN + t * NA + n];
  float val = (gv - m) * rs * bng[0] + bnb[0];
  out[idx] = val * lw[d] + lb[d];
}

extern "C" void kernel_launch(void* const* d_in, const int* in_sizes, int n_in,
                              void* d_out, int out_size, void* d_ws, size_t ws_size,
                              hipStream_t stream) {
  const float* hist = (const float*)d_in[0];
  const int* eidx = (const int*)d_in[1];
  const float* ew = (const float*)d_in[2];
  const float* hw = (const float*)d_in[3];
  const float* hb = (const float*)d_in[4];
  const float* wq = (const float*)d_in[5];
  const float* bq = (const float*)d_in[6];
  const float* wk = (const float*)d_in[7];
  const float* bk = (const float*)d_in[8];
  const float* wv = (const float*)d_in[9];
  const float* bv = (const float*)d_in[10];
  const float* wo = (const float*)d_in[11];
  const float* bo = (const float*)d_in[12];
  const float* ln1g = (const float*)d_in[13];
  const float* ln1b = (const float*)d_in[14];
  const float* w1 = (const float*)d_in[15];
  const float* b1 = (const float*)d_in[16];
  const float* w2 = (const float*)d_in[17];
  const float* b2 = (const float*)d_in[18];
  const float* ln2g = (const float*)d_in[19];
  const float* ln2b = (const float*)d_in[20];
  const float* bng = (const float*)d_in[21];
  const float* bnb = (const float*)d_in[22];
  const float* lgw = (const float*)d_in[23];
  const float* lgb = (const float*)d_in[24];
  float* out = (float*)d_out;

  float* ws = (float*)d_ws;
  const size_t NE = NE_;
  float* bx = ws + 0 * NE;
  float* be = ws + 1 * NE;
  float* h1 = ws + 2 * NE;
  float* obuf = ws + 3 * NE;  // attention output [row][128]
  float* ffmid = ws + 3 * NE; // 4NE, overlaps dead obuf (sequential deps)
  float* bs_ = ws + 7 * NE;
  float* bg_ = bs_ + NTOT;
  float* bst = bg_ + NTOT;
  float* pbias = bst + 2;
  const int LW = 196608;
  __bf16* whiB = (__bf16*)(pbias + L_ * QLD);
  __bf16* wloB = whiB + (size_t)L_ * LW;

  convert_weights<<<(L_ * LW + 255) / 256, 256, 0, stream>>>(
      wq, wk, wv, wo, w1, w2, whiB, wloB);
  bias_pack<<<(L_ * QLD + 255) / 256, 256, 0, stream>>>(bq, bk, bv, pbias);
  embed_kernel<<<(NTOT * D_) / 256, 256, 0, stream>>>(hist, hw, hb, bx, be);

  for (int l = 0; l < L_; ++l) {
    const __bf16* hiL = whiB + (size_t)l * LW;
    const __bf16* loL = wloB + (size_t)l * LW;
    attn_fused<<<B_ * NA * H_, 256, 0, stream>>>(
        be, hiL, loL, pbias + l * QLD, obuf);
    gemm_ln<128><<<dim3(1, NTOT / 64), 256, 0, stream>>>(
        obuf, 128, hiL + 49152, loL + 49152, bo + l * D_, be,
        ln1g + l * D_, ln1b + l * D_, h1);
    gemm_big<1, 128><<<dim3(4, NTOT / 128), 256, 0, stream>>>(
        h1, 128, hiL + 65536, loL + 65536, b1 + l * DFF, ffmid, 512);
    if (l < L_ - 1) {
      ff2_ln<0><<<dim3(1, NTOT / 64), 256, 0, stream>>>(
          ffmid, hiL + 131072, loL + 131072, b2 + l * D_, h1,
          ln2g + l * D_, ln2b + l * D_, be, nullptr, nullptr);
    } else {
      ff2_ln<1><<<dim3(1, NTOT / 64), 256, 0, stream>>>(
          ffmid, hiL + 131072, loL + 131072, b2 + l * D_, h1,
          ln2g + l * D_, ln2b + l * D_, be, bx, bs_);
    }
  }

  hipMemsetAsync(bg_, 0, ((size_t)B_ * NN + 2) * sizeof(float), stream);
  scatter_kernel<<<(B_ * E_) / 256, 256, 0, stream>>>(bs_, eidx, ew, bg_);
  stats_partial<<<(B_ * NN) / 256, 256, 0, stream>>>(bg_, bst);
  final_kernel<<<(NTOT * D_) / 256, 256, 0, stream>>>(bg_, bst, bng, bnb, lgw, lgb, out);
}

// Round 11
// 499.893 us; speedup vs baseline: 1.2213x; 1.0103x over previous
//
#include <hip/hip_runtime.h>
#include <hip/hip_bf16.h>
#include <math.h>

#define EPS_ 1e-5f
constexpr int B_ = 4, NA = 64, T_ = 128, D_ = 128, H_ = 8, L_ = 3, DFF = 512, E_ = 65536;
constexpr int DH = D_ / H_;        // 16
constexpr int NN = T_ * NA;        // 8192
constexpr int NTOT = B_ * NA * T_; // 32768
constexpr int QLD = 384;           // packed QKV bias stride
constexpr size_t NE_ = (size_t)NTOT * D_;

typedef __bf16 bf16x8 __attribute__((ext_vector_type(8)));
typedef float f32x4 __attribute__((ext_vector_type(4)));

// ---------------- embed: x = hist@W + b ; e = x + posenc ----------------
__global__ __launch_bounds__(256) void embed_kernel(
    const float* __restrict__ hist, const float* __restrict__ w,
    const float* __restrict__ b, float* __restrict__ x, float* __restrict__ e) {
  int idx = blockIdx.x * 256 + threadIdx.x;
  if (idx >= NTOT * D_) return;
  int d = idx & (D_ - 1);
  int r = idx >> 7;
  int t = r & (T_ - 1);
  const float* hp = hist + (size_t)r * 3;
  float acc = b[d];
  acc += hp[0] * w[0 * D_ + d];
  acc += hp[1] * w[1 * D_ + d];
  acc += hp[2] * w[2 * D_ + d];
  x[idx] = acc;
  int p = d >> 1;
  float ang = (float)t * expf(-logf(10000.f) * (2.f * (float)p) / (float)D_);
  float pe = (d & 1) ? cosf(ang) : sinf(ang);
  e[idx] = acc + pe;
}

// ---------------- weight split into FRAGMENT-LINEAR bf16 hi/lo ----------------
__global__ __launch_bounds__(256) void convert_weights(
    const float* __restrict__ wq, const float* __restrict__ wk,
    const float* __restrict__ wv, const float* __restrict__ wo,
    const float* __restrict__ w1, const float* __restrict__ w2,
    __bf16* __restrict__ hi, __bf16* __restrict__ lo) {
  const int LW = 196608;
  int idx = blockIdx.x * 256 + threadIdx.x;
  if (idx >= L_ * LW) return;
  int l = idx / LW;
  int rem = idx - l * LW;
  float src;
  int n, k, K, segoff;
  if (rem < 49152) { // qkv
    n = rem >> 7; k = rem & 127; K = 128; segoff = 0;
    int which = n >> 7, nl = n & 127;
    const float* W = (which == 0) ? wq : (which == 1) ? wk : wv;
    src = W[(size_t)l * 16384 + k * 128 + nl];
  } else if (rem < 65536) { // wo
    int r2 = rem - 49152;
    n = r2 >> 7; k = r2 & 127; K = 128; segoff = 49152;
    src = wo[(size_t)l * 16384 + k * 128 + n];
  } else if (rem < 131072) { // w1
    int r2 = rem - 65536;
    n = r2 >> 7; k = r2 & 127; K = 128; segoff = 65536;
    src = w1[(size_t)l * 65536 + k * 512 + n];
  } else { // w2
    int r2 = rem - 131072;
    n = r2 >> 9; k = r2 & 511; K = 512; segoff = 131072;
    src = w2[(size_t)l * 65536 + k * 128 + n];
  }
  int nt = n >> 4, kt = k >> 5;
  int lane = ((k >> 3) & 3) * 16 + (n & 15);
  int j = k & 7;
  int dst = l * LW + segoff + ((nt * (K / 32) + kt) * 64 + lane) * 8 + j;
  __bf16 h = (__bf16)src;
  hi[dst] = h;
  lo[dst] = (__bf16)(src - (float)h);
}

// ---------------- pack QKV biases ----------------
__global__ __launch_bounds__(256) void bias_pack(
    const float* __restrict__ bq, const float* __restrict__ bk,
    const float* __restrict__ bv, float* __restrict__ pb) {
  int idx = blockIdx.x * 256 + threadIdx.x;
  if (idx >= L_ * QLD) return;
  int l = idx / QLD, n = idx - l * QLD;
  int which = n >> 7, nl = n & 127;
  const float* src = (which == 0) ? bq : (which == 1) ? bk : bv;
  pb[idx] = src[l * 128 + nl];
}

__device__ __forceinline__ void split8(const float* __restrict__ p,
                                       bf16x8& hi, bf16x8& lo) {
  float4 x0 = *(const float4*)p;
  float4 x1 = *(const float4*)(p + 4);
  float xv[8] = {x0.x, x0.y, x0.z, x0.w, x1.x, x1.y, x1.z, x1.w};
#pragma unroll
  for (int j = 0; j < 8; ++j) {
    __bf16 h = (__bf16)xv[j];
    hi[j] = h;
    lo[j] = (__bf16)(xv[j] - (float)h);
  }
}

// ---------------- MFMA GEMM, 128x128 tile (wave 64x64), frag-linear W [r12, r0-proven] ----------------
template <int EPI, int K>
__global__ __launch_bounds__(256) void gemm_big(
    const float* __restrict__ A, int lda,
    const __bf16* __restrict__ Whi, const __bf16* __restrict__ Wlo,
    const float* __restrict__ bias,
    float* __restrict__ C, int ldc) {
  const int wave = threadIdx.x >> 6;
  const int lane = threadIdx.x & 63;
  const int m16 = lane & 15;
  const int quad = lane >> 4;
  const int wrow = wave >> 1, wcol = wave & 1;
  const int row0 = blockIdx.y * 128 + wrow * 64;
  const int col0 = blockIdx.x * 128 + wcol * 64;
  const int ctb = col0 >> 4;

  f32x4 acc[4][4] = {};
#pragma unroll
  for (int k0 = 0; k0 < K; k0 += 32) {
    bf16x8 ahi[4], alo[4];
#pragma unroll
    for (int mf = 0; mf < 4; ++mf)
      split8(A + (size_t)(row0 + mf * 16 + m16) * lda + k0 + quad * 8, ahi[mf], alo[mf]);
    bf16x8 bhi[4], blo[4];
#pragma unroll
    for (int nf = 0; nf < 4; ++nf) {
      size_t off = ((size_t)(ctb + nf) * (K / 32) + (k0 >> 5)) * 512 + lane * 8;
      bhi[nf] = *(const bf16x8*)(Whi + off);
      blo[nf] = *(const bf16x8*)(Wlo + off);
    }
#pragma unroll
    for (int mf = 0; mf < 4; ++mf)
#pragma unroll
      for (int nf = 0; nf < 4; ++nf) {
        acc[mf][nf] = __builtin_amdgcn_mfma_f32_16x16x32_bf16(ahi[mf], bhi[nf], acc[mf][nf], 0, 0, 0);
        acc[mf][nf] = __builtin_amdgcn_mfma_f32_16x16x32_bf16(ahi[mf], blo[nf], acc[mf][nf], 0, 0, 0);
        acc[mf][nf] = __builtin_amdgcn_mfma_f32_16x16x32_bf16(alo[mf], bhi[nf], acc[mf][nf], 0, 0, 0);
      }
  }
#pragma unroll
  for (int mf = 0; mf < 4; ++mf)
#pragma unroll
    for (int nf = 0; nf < 4; ++nf) {
      int c = col0 + nf * 16 + m16;
      float bj = bias[c];
#pragma unroll
      for (int reg = 0; reg < 4; ++reg) {
        int r = row0 + mf * 16 + quad * 4 + reg;
        float v = acc[mf][nf][reg] + bj;
        if (EPI == 1) v = fmaxf(v, 0.f);
        C[(size_t)r * ldc + c] = v;
      }
    }
}

// ---------------- GEMM + bias + resid + LayerNorm; block 64x128, register A [r12] ----------------
template <int K>
__global__ __launch_bounds__(256) void gemm_ln(
    const float* __restrict__ A, int lda,
    const __bf16* __restrict__ Whi, const __bf16* __restrict__ Wlo,
    const float* __restrict__ bias, const float* __restrict__ resid,
    const float* __restrict__ lng, const float* __restrict__ lnb,
    float* __restrict__ C) {
  const int wave = threadIdx.x >> 6;
  const int lane = threadIdx.x & 63;
  const int m16 = lane & 15;
  const int quad = lane >> 4;
  const int wrow = wave >> 1, wcol = wave & 1;
  const int row0 = blockIdx.y * 64 + wrow * 32;
  const int col0 = wcol * 64;
  const int ctb = wcol * 4;

  f32x4 acc[2][4] = {};
#pragma unroll
  for (int k0 = 0; k0 < K; k0 += 32) {
    bf16x8 ahi[2], alo[2];
#pragma unroll
    for (int mf = 0; mf < 2; ++mf)
      split8(A + (size_t)(row0 + mf * 16 + m16) * lda + k0 + quad * 8, ahi[mf], alo[mf]);
    bf16x8 bhi[4], blo[4];
#pragma unroll
    for (int nf = 0; nf < 4; ++nf) {
      size_t off = ((size_t)(ctb + nf) * (K / 32) + (k0 >> 5)) * 512 + lane * 8;
      bhi[nf] = *(const bf16x8*)(Whi + off);
      blo[nf] = *(const bf16x8*)(Wlo + off);
    }
#pragma unroll
    for (int mf = 0; mf < 2; ++mf)
#pragma unroll
      for (int nf = 0; nf < 4; ++nf) {
        acc[mf][nf] = __builtin_amdgcn_mfma_f32_16x16x32_bf16(ahi[mf], bhi[nf], acc[mf][nf], 0, 0, 0);
        acc[mf][nf] = __builtin_amdgcn_mfma_f32_16x16x32_bf16(ahi[mf], blo[nf], acc[mf][nf], 0, 0, 0);
        acc[mf][nf] = __builtin_amdgcn_mfma_f32_16x16x32_bf16(alo[mf], bhi[nf], acc[mf][nf], 0, 0, 0);
      }
  }
  __shared__ float rs[64][2], rq[64][2];
#pragma unroll
  for (int mf = 0; mf < 2; ++mf)
#pragma unroll
    for (int reg = 0; reg < 4; ++reg) {
      int lr = wrow * 32 + mf * 16 + quad * 4 + reg;
      int gr = blockIdx.y * 64 + lr;
      float s = 0.f, qq = 0.f;
#pragma unroll
      for (int nf = 0; nf < 4; ++nf) {
        int c = col0 + nf * 16 + m16;
        float v = acc[mf][nf][reg] + bias[c] + resid[(size_t)gr * 128 + c];
        acc[mf][nf][reg] = v;
        s += v;
        qq += v * v;
      }
#pragma unroll
      for (int off = 1; off < 16; off <<= 1) {
        s += __shfl_xor(s, off, 64);
        qq += __shfl_xor(qq, off, 64);
      }
      if (m16 == 0) { rs[lr][wcol] = s; rq[lr][wcol] = qq; }
    }
  __syncthreads();
#pragma unroll
  for (int mf = 0; mf < 2; ++mf)
#pragma unroll
    for (int reg = 0; reg < 4; ++reg) {
      int lr = wrow * 32 + mf * 16 + quad * 4 + reg;
      int gr = blockIdx.y * 64 + lr;
      float mean = (rs[lr][0] + rs[lr][1]) * (1.f / 128.f);
      float var = (rq[lr][0] + rq[lr][1]) * (1.f / 128.f) - mean * mean;
      float rstd = rsqrtf(var + EPS_);
#pragma unroll
      for (int nf = 0; nf < 4; ++nf) {
        int c = col0 + nf * 16 + m16;
        C[(size_t)gr * 128 + c] = (acc[mf][nf][reg] - mean) * rstd * lng[c] + lnb[c];
      }
    }
}

// ---------------- FF2 + LN (staged A, K=512) [r12]; SDOT fuses gating dot [r15] ----------------
template <int SDOT>
__global__ __launch_bounds__(256) void ff2_ln(
    const float* __restrict__ A, // ffmid [M][512]
    const __bf16* __restrict__ Whi, const __bf16* __restrict__ Wlo,
    const float* __restrict__ bias, const float* __restrict__ resid,
    const float* __restrict__ lng, const float* __restrict__ lnb,
    float* __restrict__ C,
    const float* __restrict__ bx, float* __restrict__ sdst) {
  const int wave = threadIdx.x >> 6;
  const int lane = threadIdx.x & 63;
  const int m16 = lane & 15;
  const int quad = lane >> 4;
  const int wrow = wave >> 1, wcol = wave & 1;
  const int grow0 = blockIdx.y * 64;
  const int lrow0 = wrow * 32;
  const int col0 = wcol * 64;
  const int ctb = wcol * 4;

  __shared__ float As[64][129];

  f32x4 acc[2][4] = {};
  for (int kc = 0; kc < 4; ++kc) {
    if (kc) __syncthreads();
#pragma unroll
    for (int u = 0; u < 8; ++u) {
      int unit = threadIdx.x + u * 256;
      int r = unit >> 5, c4 = unit & 31;
      float4 v = *(const float4*)(A + (size_t)(grow0 + r) * 512 + kc * 128 + c4 * 4);
      As[r][c4 * 4 + 0] = v.x;
      As[r][c4 * 4 + 1] = v.y;
      As[r][c4 * 4 + 2] = v.z;
      As[r][c4 * 4 + 3] = v.w;
    }
    __syncthreads();
#pragma unroll
    for (int kt = 0; kt < 4; ++kt) {
      bf16x8 ahi[2], alo[2];
#pragma unroll
      for (int mf = 0; mf < 2; ++mf)
        split8(&As[lrow0 + mf * 16 + m16][kt * 32 + quad * 8], ahi[mf], alo[mf]);
      bf16x8 bhi[4], blo[4];
#pragma unroll
      for (int nf = 0; nf < 4; ++nf) {
        size_t off = ((size_t)(ctb + nf) * 16 + (kc * 4 + kt)) * 512 + lane * 8;
        bhi[nf] = *(const bf16x8*)(Whi + off);
        blo[nf] = *(const bf16x8*)(Wlo + off);
      }
#pragma unroll
      for (int mf = 0; mf < 2; ++mf)
#pragma unroll
        for (int nf = 0; nf < 4; ++nf) {
          acc[mf][nf] = __builtin_amdgcn_mfma_f32_16x16x32_bf16(ahi[mf], bhi[nf], acc[mf][nf], 0, 0, 0);
          acc[mf][nf] = __builtin_amdgcn_mfma_f32_16x16x32_bf16(ahi[mf], blo[nf], acc[mf][nf], 0, 0, 0);
          acc[mf][nf] = __builtin_amdgcn_mfma_f32_16x16x32_bf16(alo[mf], bhi[nf], acc[mf][nf], 0, 0, 0);
        }
    }
  }
  __shared__ float rs[64][2], rq[64][2];
  __shared__ float sd[64][2];
#pragma unroll
  for (int mf = 0; mf < 2; ++mf)
#pragma unroll
    for (int reg = 0; reg < 4; ++reg) {
      int lr = lrow0 + mf * 16 + quad * 4 + reg;
      int gr = grow0 + lr;
      float s = 0.f, qq = 0.f;
#pragma unroll
      for (int nf = 0; nf < 4; ++nf) {
        int c = col0 + nf * 16 + m16;
        float v = acc[mf][nf][reg] + bias[c] + resid[(size_t)gr * 128 + c];
        acc[mf][nf][reg] = v;
        s += v;
        qq += v * v;
      }
#pragma unroll
      for (int off = 1; off < 16; off <<= 1) {
        s += __shfl_xor(s, off, 64);
        qq += __shfl_xor(qq, off, 64);
      }
      if (m16 == 0) { rs[lr][wcol] = s; rq[lr][wcol] = qq; }
    }
  __syncthreads();
#pragma unroll
  for (int mf = 0; mf < 2; ++mf)
#pragma unroll
    for (int reg = 0; reg < 4; ++reg) {
      int lr = lrow0 + mf * 16 + quad * 4 + reg;
      int gr = grow0 + lr;
      float mean = (rs[lr][0] + rs[lr][1]) * (1.f / 128.f);
      float var = (rq[lr][0] + rq[lr][1]) * (1.f / 128.f) - mean * mean;
      float rstd = rsqrtf(var + EPS_);
      float sdp = 0.f;
#pragma unroll
      for (int nf = 0; nf < 4; ++nf) {
        int c = col0 + nf * 16 + m16;
        float v = (acc[mf][nf][reg] - mean) * rstd * lng[c] + lnb[c];
        C[(size_t)gr * 128 + c] = v;
        if (SDOT) sdp += v * bx[(size_t)gr * 128 + c];
      }
      if (SDOT) {
#pragma unroll
        for (int off = 1; off < 16; off <<= 1) sdp += __shfl_xor(sdp, off, 64);
        if (m16 == 0) sd[lr][wcol] = sdp;
      }
    }
  if (SDOT) {
    __syncthreads();
    if (threadIdx.x < 64) {
      int lr = threadIdx.x;
      int gr = grow0 + lr;
      float sv = sd[lr][0] + sd[lr][1];
      int t = gr & (T_ - 1);
      int bn = gr >> 7;
      int n = bn & (NA - 1);
      int b = bn >> 6;
      sdst[(size_t)b * NN + t * NA + n] = sv;
    }
  }
}

// ---------------- FUSED QKV-GEMM + attention [r24: K/V time-share one LDS region] ----------------
// r23 structure (the 505us winner) with one change: K and V never need LDS simultaneously
// (K fully consumed by QK^T before V is first read by PV), so V is held in the mini-GEMM's
// registers until after QK^T and then staged into K's 8KB region. LDS 51.2 -> 43.0 KB =>
// 3 blocks/CU (was 2) at the cost of two extra barriers. V values, layout indices, and all
// MFMA operands are bitwise identical to r23. (r10 resubmission: container flake, kernel
// audited — all LDS indices in-bounds, disjoint write sets, no new host API.)
__global__ __launch_bounds__(256) void attn_fused(
    const float* __restrict__ A,       // be [NTOT][128]
    const __bf16* __restrict__ Whi, const __bf16* __restrict__ Wlo, // layer qkv segment
    const float* __restrict__ pb,      // packed qkv bias [384]
    float* __restrict__ O) {           // [NTOT][128]
  const int h = blockIdx.x & (H_ - 1);
  const int bn = blockIdx.x >> 3;
  const int wave = threadIdx.x >> 6;
  const int lane = threadIdx.x & 63;
  const int m16 = lane & 15;
  const int quad = lane >> 4;
  const int row0 = wave * 32;
  const float* Ab = A + (size_t)bn * T_ * 128;

  __shared__ __bf16 Plds[4][32][136];
  __shared__ __bf16 KVH[8][32][8], KVL[8][32][8]; // K then (post-QK^T) V, time-shared
  __bf16* QHw = &Plds[wave][0][0];                // wave-private Q: [2][32][8] (aliased)
  __bf16* QLw = QHw + 512;
  __bf16* kvh = &KVH[0][0][0];
  __bf16* kvl = &KVL[0][0][0];

  // ---- mini-GEMM: rows [row0, row0+32) x {Q,K,V} cols [h*16, h*16+16)
  f32x4 qkv[2][3] = {}; // [mf][seg]
#pragma unroll
  for (int k0 = 0; k0 < 128; k0 += 32) {
    bf16x8 ahi[2], alo[2];
#pragma unroll
    for (int mf = 0; mf < 2; ++mf)
      split8(Ab + (size_t)(row0 + mf * 16 + m16) * 128 + k0 + quad * 8, ahi[mf], alo[mf]);
    bf16x8 bhi[3], blo[3];
#pragma unroll
    for (int s = 0; s < 3; ++s) {
      size_t off = ((size_t)(s * 8 + h) * 4 + (k0 >> 5)) * 512 + lane * 8; // ctb = s*8+h
      bhi[s] = *(const bf16x8*)(Whi + off);
      blo[s] = *(const bf16x8*)(Wlo + off);
    }
#pragma unroll
    for (int mf = 0; mf < 2; ++mf)
#pragma unroll
      for (int s = 0; s < 3; ++s) {
        qkv[mf][s] = __builtin_amdgcn_mfma_f32_16x16x32_bf16(ahi[mf], bhi[s], qkv[mf][s], 0, 0, 0);
        qkv[mf][s] = __builtin_amdgcn_mfma_f32_16x16x32_bf16(ahi[mf], blo[s], qkv[mf][s], 0, 0, 0);
        qkv[mf][s] = __builtin_amdgcn_mfma_f32_16x16x32_bf16(alo[mf], bhi[s], qkv[mf][s], 0, 0, 0);
      }
  }

  // ---- stage Q (wave-private) + K (shared); V stays in registers until after QK^T
#pragma unroll
  for (int mf = 0; mf < 2; ++mf)
#pragma unroll
    for (int reg = 0; reg < 4; ++reg) {
      const int tl = mf * 16 + quad * 4 + reg; // local row 0..31
      const int t = row0 + tl;                 // block row 0..127
      const int dh = m16;
      { // Q -> wave-private
        float v = qkv[mf][0][reg] + pb[h * 16 + dh];
        __bf16 hh = (__bf16)v;
        __bf16 ll = (__bf16)(v - (float)hh);
        int idx = mf * 256 + ((dh >> 3) * 16 + (tl & 15)) * 8 + (dh & 7);
        QHw[idx] = hh;
        QLw[idx] = ll;
      }
      { // K -> shared (K layout: [t>>4][(dh>>3)*16 + (t&15)][dh&7])
        float v = qkv[mf][1][reg] + pb[128 + h * 16 + dh];
        __bf16 hh = (__bf16)v;
        __bf16 ll = (__bf16)(v - (float)hh);
        int idx = ((t >> 4) * 32 + (dh >> 3) * 16 + (t & 15)) * 8 + (dh & 7);
        kvh[idx] = hh;
        kvl[idx] = ll;
      }
    }

  // ---- read own Q A-frags back (wave-private; same-wave LDS dependency)
  bf16x8 qhi[2], qlo[2];
#pragma unroll
  for (int mf = 0; mf < 2; ++mf) {
    if (quad < 2) {
      int idx = mf * 256 + (quad * 16 + m16) * 8;
      qhi[mf] = *(const bf16x8*)&QHw[idx];
      qlo[mf] = *(const bf16x8*)&QLw[idx];
    } else {
#pragma unroll
      for (int j = 0; j < 8; ++j) { qhi[mf][j] = (__bf16)0.f; qlo[mf][j] = (__bf16)0.f; }
    }
  }
  __syncthreads(); // K staging visible to all waves

  f32x4 acc[2][8] = {};
#pragma unroll
  for (int nf = 0; nf < 8; ++nf) {
    bf16x8 khi, klo;
    if (quad < 2) {
      khi = *(const bf16x8*)&kvh[(nf * 32 + lane) * 8]; // lane in [0,32)
      klo = *(const bf16x8*)&kvl[(nf * 32 + lane) * 8];
    } else {
#pragma unroll
      for (int j = 0; j < 8; ++j) { khi[j] = (__bf16)0.f; klo[j] = (__bf16)0.f; }
    }
#pragma unroll
    for (int mf = 0; mf < 2; ++mf) {
      acc[mf][nf] = __builtin_amdgcn_mfma_f32_16x16x32_bf16(qhi[mf], khi, acc[mf][nf], 0, 0, 0);
      acc[mf][nf] = __builtin_amdgcn_mfma_f32_16x16x32_bf16(qhi[mf], klo, acc[mf][nf], 0, 0, 0);
      acc[mf][nf] = __builtin_amdgcn_mfma_f32_16x16x32_bf16(qlo[mf], khi, acc[mf][nf], 0, 0, 0);
    }
  }
  __syncthreads(); // all waves done reading K -> region reusable for V

  // ---- stage V into the K region (V layout: [(t>>5)*64 + (rem>>3)*16 + dh][rem&7])
#pragma unroll
  for (int mf = 0; mf < 2; ++mf)
#pragma unroll
    for (int reg = 0; reg < 4; ++reg) {
      const int t = row0 + mf * 16 + quad * 4 + reg;
      const int dh = m16;
      float v = qkv[mf][2][reg] + pb[256 + h * 16 + dh];
      __bf16 hh = (__bf16)v;
      __bf16 ll = (__bf16)(v - (float)hh);
      int kc = t >> 5, rem = t & 31;
      int idx = (kc * 64 + (rem >> 3) * 16 + dh) * 8 + (rem & 7);
      kvh[idx] = hh;
      kvl[idx] = ll;
    }

  // ---- softmax (register-only; overlaps other waves' V stores)
  const float scale = 0.25f;
#pragma unroll
  for (int mf = 0; mf < 2; ++mf)
#pragma unroll
    for (int reg = 0; reg < 4; ++reg) {
      float mx = -1e30f;
#pragma unroll
      for (int nf = 0; nf < 8; ++nf) mx = fmaxf(mx, acc[mf][nf][reg]);
#pragma unroll
      for (int off = 1; off < 16; off <<= 1) mx = fmaxf(mx, __shfl_xor(mx, off, 64));
      float sum = 0.f;
#pragma unroll
      for (int nf = 0; nf < 8; ++nf) {
        float e = __expf((acc[mf][nf][reg] - mx) * scale);
        acc[mf][nf][reg] = e;
        sum += e;
      }
#pragma unroll
      for (int off = 1; off < 16; off <<= 1) sum += __shfl_xor(sum, off, 64);
      float inv = 1.f / sum;
#pragma unroll
      for (int nf = 0; nf < 8; ++nf) acc[mf][nf][reg] *= inv;
    }
  __syncthreads(); // V staging visible to all waves

#pragma unroll
  for (int mf = 0; mf < 2; ++mf)
#pragma unroll
    for (int nf = 0; nf < 8; ++nf)
#pragma unroll
      for (int reg = 0; reg < 4; ++reg)
        Plds[wave][mf * 16 + quad * 4 + reg][nf * 16 + m16] = (__bf16)acc[mf][nf][reg];

  f32x4 oacc[2] = {};
#pragma unroll
  for (int kc = 0; kc < 4; ++kc) {
    bf16x8 pa0 = *(const bf16x8*)&Plds[wave][m16][kc * 32 + quad * 8];
    bf16x8 pa1 = *(const bf16x8*)&Plds[wave][16 + m16][kc * 32 + quad * 8];
    bf16x8 vhi = *(const bf16x8*)&kvh[(kc * 64 + lane) * 8];
    bf16x8 vlo = *(const bf16x8*)&kvl[(kc * 64 + lane) * 8];
    oacc[0] = __builtin_amdgcn_mfma_f32_16x16x32_bf16(pa0, vhi, oacc[0], 0, 0, 0);
    oacc[0] = __builtin_amdgcn_mfma_f32_16x16x32_bf16(pa0, vlo, oacc[0], 0, 0, 0);
    oacc[1] = __builtin_amdgcn_mfma_f32_16x16x32_bf16(pa1, vhi, oacc[1], 0, 0, 0);
    oacc[1] = __builtin_amdgcn_mfma_f32_16x16x32_bf16(pa1, vlo, oacc[1], 0, 0, 0);
  }

#pragma unroll
  for (int mf = 0; mf < 2; ++mf)
#pragma unroll
    for (int reg = 0; reg < 4; ++reg) {
      int r = row0 + mf * 16 + quad * 4 + reg;
      O[((size_t)bn * T_ + r) * 128 + h * 16 + m16] = oacc[mf][reg];
    }
}

// ---------------- edge scatter ----------------
__global__ __launch_bounds__(256) void scatter_kernel(
    const float* __restrict__ s, const int* __restrict__ ei,
    const float* __restrict__ ew, float* __restrict__ g) {
  int idx = blockIdx.x * 256 + threadIdx.x;
  if (idx >= B_ * E_) return;
  int b = idx >> 16;
  int e = idx & (E_ - 1);
  int src = ei[(size_t)b * 2 * E_ + e];
  int dst = ei[(size_t)b * 2 * E_ + E_ + e];
  float w = ew[(size_t)b * E_ + e];
  atomicAdd(&g[(size_t)b * NN + dst], w * s[(size_t)b * NN + src]);
}

// ---------------- partial sums for global mean/var ----------------
__global__ __launch_bounds__(256) void stats_partial(
    const float* __restrict__ g, float* __restrict__ st) {
  int i = blockIdx.x * 256 + threadIdx.x;
  float v = g[i];
  float sum = v, sq = v * v;
#pragma unroll
  for (int off = 32; off; off >>= 1) {
    sum += __shfl_down(sum, off, 64);
    sq += __shfl_down(sq, off, 64);
  }
  __shared__ float s1[4], s2[4];
  int w = threadIdx.x >> 6;
  if ((threadIdx.x & 63) == 0) { s1[w] = sum; s2[w] = sq; }
  __syncthreads();
  if (threadIdx.x == 0) {
    atomicAdd(&st[0], s1[0] + s1[1] + s1[2] + s1[3]);
    atomicAdd(&st[1], s2[0] + s2[1] + s2[2] + s2[3]);
  }
}

// ---------------- final (fp32 out) ----------------
__global__ __launch_bounds__(256) void final_kernel(
    const float* __restrict__ g, const float* __restrict__ st,
    const float* __restrict__ bng, const float* __restrict__ bnb,
    const float* __restrict__ lw, const float* __restrict__ lb,
    float* __restrict__ out) {
  int idx = blockIdx.x * 256 + threadIdx.x;
  if (idx >= NTOT * D_) return;
  int d = idx & (D_ - 1);
  int r = idx >> 7;
  int t = r & (T_ - 1);
  int bn = r >> 7;
  int n = bn & (NA - 1);
  int b = bn >> 6;
  const float invn = 1.f / (float)(B_ * NN);
  float m = st[0] * invn;
  float var = st[1] * invn - m * m;
  float rs = rsqrtf(var + EPS_);
  float gv = g[(size_t)b * NN + t * NA + n];
  float val = (gv - m) * rs * bng[0] + bnb[0];
  out[idx] = val * lw[d] + lb[d];
}

extern "C" void kernel_launch(void* const* d_in, const int* in_sizes, int n_in,
                              void* d_out, int out_size, void* d_ws, size_t ws_size,
                              hipStream_t stream) {
  const float* hist = (const float*)d_in[0];
  const int* eidx = (const int*)d_in[1];
  const float* ew = (const float*)d_in[2];
  const float* hw = (const float*)d_in[3];
  const float* hb = (const float*)d_in[4];
  const float* wq = (const float*)d_in[5];
  const float* bq = (const float*)d_in[6];
  const float* wk = (const float*)d_in[7];
  const float* bk = (const float*)d_in[8];
  const float* wv = (const float*)d_in[9];
  const float* bv = (const float*)d_in[10];
  const float* wo = (const float*)d_in[11];
  const float* bo = (const float*)d_in[12];
  const float* ln1g = (const float*)d_in[13];
  const float* ln1b = (const float*)d_in[14];
  const float* w1 = (const float*)d_in[15];
  const float* b1 = (const float*)d_in[16];
  const float* w2 = (const float*)d_in[17];
  const float* b2 = (const float*)d_in[18];
  const float* ln2g = (const float*)d_in[19];
  const float* ln2b = (const float*)d_in[20];
  const float* bng = (const float*)d_in[21];
  const float* bnb = (const float*)d_in[22];
  const float* lgw = (const float*)d_in[23];
  const float* lgb = (const float*)d_in[24];
  float* out = (float*)d_out;

  float* ws = (float*)d_ws;
  const size_t NE = NE_;
  float* bx = ws + 0 * NE;
  float* be = ws + 1 * NE;
  float* h1 = ws + 2 * NE;
  float* obuf = ws + 3 * NE;  // attention output [row][128]
  float* ffmid = ws + 3 * NE; // 4NE, overlaps dead obuf (sequential deps)
  float* bs_ = ws + 7 * NE;
  float* bg_ = bs_ + NTOT;
  float* bst = bg_ + NTOT;
  float* pbias = bst + 2;
  const int LW = 196608;
  __bf16* whiB = (__bf16*)(pbias + L_ * QLD);
  __bf16* wloB = whiB + (size_t)L_ * LW;

  convert_weights<<<(L_ * LW + 255) / 256, 256, 0, stream>>>(
      wq, wk, wv, wo, w1, w2, whiB, wloB);
  bias_pack<<<(L_ * QLD + 255) / 256, 256, 0, stream>>>(bq, bk, bv, pbias);
  embed_kernel<<<(NTOT * D_) / 256, 256, 0, stream>>>(hist, hw, hb, bx, be);

  for (int l = 0; l < L_; ++l) {
    const __bf16* hiL = whiB + (size_t)l * LW;
    const __bf16* loL = wloB + (size_t)l * LW;
    attn_fused<<<B_ * NA * H_, 256, 0, stream>>>(
        be, hiL, loL, pbias + l * QLD, obuf);
    gemm_ln<128><<<dim3(1, NTOT / 64), 256, 0, stream>>>(
        obuf, 128, hiL + 49152, loL + 49152, bo + l * D_, be,
        ln1g + l * D_, ln1b + l * D_, h1);
    gemm_big<1, 128><<<dim3(4, NTOT / 128), 256, 0, stream>>>(
        h1, 128, hiL + 65536, loL + 65536, b1 + l * DFF, ffmid, 512);
    if (l < L_ - 1) {
      ff2_ln<0><<<dim3(1, NTOT / 64), 256, 0, stream>>>(
          ffmid, hiL + 131072, loL + 131072, b2 + l * D_, h1,
          ln2g + l * D_, ln2b + l * D_, be, nullptr, nullptr);
    } else {
      ff2_ln<1><<<dim3(1, NTOT / 64), 256, 0, stream>>>(
          ffmid, hiL + 131072, loL + 131072, b2 + l * D_, h1,
          ln2g + l * D_, ln2b + l * D_, be, bx, bs_);
    }
  }

  hipMemsetAsync(bg_, 0, ((size_t)B_ * NN + 2) * sizeof(float), stream);
  scatter_kernel<<<(B_ * E_) / 256, 256, 0, stream>>>(bs_, eidx, ew, bg_);
  stats_partial<<<(B_ * NN) / 256, 256, 0, stream>>>(bg_, bst);
  final_kernel<<<(NTOT * D_) / 256, 256, 0, stream>>>(bg_, bst, bng, bnb, lgw, lgb, out);
}

// Round 12
// 496.625 us; speedup vs baseline: 1.2293x; 1.0066x over previous
//
#include <hip/hip_runtime.h>
#include <hip/hip_bf16.h>
#include <math.h>

#define EPS_ 1e-5f
constexpr int B_ = 4, NA = 64, T_ = 128, D_ = 128, H_ = 8, L_ = 3, DFF = 512, E_ = 65536;
constexpr int DH = D_ / H_;        // 16
constexpr int NN = T_ * NA;        // 8192
constexpr int NTOT = B_ * NA * T_; // 32768
constexpr int QLD = 384;           // packed QKV bias stride
constexpr size_t NE_ = (size_t)NTOT * D_;

typedef __bf16 bf16x8 __attribute__((ext_vector_type(8)));
typedef float f32x4 __attribute__((ext_vector_type(4)));

// ---------------- embed: x = hist@W + b ; e = x + posenc ----------------
__global__ __launch_bounds__(256) void embed_kernel(
    const float* __restrict__ hist, const float* __restrict__ w,
    const float* __restrict__ b, float* __restrict__ x, float* __restrict__ e) {
  int idx = blockIdx.x * 256 + threadIdx.x;
  if (idx >= NTOT * D_) return;
  int d = idx & (D_ - 1);
  int r = idx >> 7;
  int t = r & (T_ - 1);
  const float* hp = hist + (size_t)r * 3;
  float acc = b[d];
  acc += hp[0] * w[0 * D_ + d];
  acc += hp[1] * w[1 * D_ + d];
  acc += hp[2] * w[2 * D_ + d];
  x[idx] = acc;
  int p = d >> 1;
  float ang = (float)t * expf(-logf(10000.f) * (2.f * (float)p) / (float)D_);
  float pe = (d & 1) ? cosf(ang) : sinf(ang);
  e[idx] = acc + pe;
}

// ---------------- weight split into FRAGMENT-LINEAR bf16 hi/lo ----------------
__global__ __launch_bounds__(256) void convert_weights(
    const float* __restrict__ wq, const float* __restrict__ wk,
    const float* __restrict__ wv, const float* __restrict__ wo,
    const float* __restrict__ w1, const float* __restrict__ w2,
    __bf16* __restrict__ hi, __bf16* __restrict__ lo) {
  const int LW = 196608;
  int idx = blockIdx.x * 256 + threadIdx.x;
  if (idx >= L_ * LW) return;
  int l = idx / LW;
  int rem = idx - l * LW;
  float src;
  int n, k, K, segoff;
  if (rem < 49152) { // qkv
    n = rem >> 7; k = rem & 127; K = 128; segoff = 0;
    int which = n >> 7, nl = n & 127;
    const float* W = (which == 0) ? wq : (which == 1) ? wk : wv;
    src = W[(size_t)l * 16384 + k * 128 + nl];
  } else if (rem < 65536) { // wo
    int r2 = rem - 49152;
    n = r2 >> 7; k = r2 & 127; K = 128; segoff = 49152;
    src = wo[(size_t)l * 16384 + k * 128 + n];
  } else if (rem < 131072) { // w1
    int r2 = rem - 65536;
    n = r2 >> 7; k = r2 & 127; K = 128; segoff = 65536;
    src = w1[(size_t)l * 65536 + k * 512 + n];
  } else { // w2
    int r2 = rem - 131072;
    n = r2 >> 9; k = r2 & 511; K = 512; segoff = 131072;
    src = w2[(size_t)l * 65536 + k * 128 + n];
  }
  int nt = n >> 4, kt = k >> 5;
  int lane = ((k >> 3) & 3) * 16 + (n & 15);
  int j = k & 7;
  int dst = l * LW + segoff + ((nt * (K / 32) + kt) * 64 + lane) * 8 + j;
  __bf16 h = (__bf16)src;
  hi[dst] = h;
  lo[dst] = (__bf16)(src - (float)h);
}

// ---------------- pack QKV biases ----------------
__global__ __launch_bounds__(256) void bias_pack(
    const float* __restrict__ bq, const float* __restrict__ bk,
    const float* __restrict__ bv, float* __restrict__ pb) {
  int idx = blockIdx.x * 256 + threadIdx.x;
  if (idx >= L_ * QLD) return;
  int l = idx / QLD, n = idx - l * QLD;
  int which = n >> 7, nl = n & 127;
  const float* src = (which == 0) ? bq : (which == 1) ? bk : bv;
  pb[idx] = src[l * 128 + nl];
}

__device__ __forceinline__ void split8(const float* __restrict__ p,
                                       bf16x8& hi, bf16x8& lo) {
  float4 x0 = *(const float4*)p;
  float4 x1 = *(const float4*)(p + 4);
  float xv[8] = {x0.x, x0.y, x0.z, x0.w, x1.x, x1.y, x1.z, x1.w};
#pragma unroll
  for (int j = 0; j < 8; ++j) {
    __bf16 h = (__bf16)xv[j];
    hi[j] = h;
    lo[j] = (__bf16)(xv[j] - (float)h);
  }
}

// ---------------- MFMA GEMM, 128x128 tile, frag-linear W [r25: 1-D grid, XCD co-location] ----------------
// Launched 1-D (NB * NY blocks); decode by = wgid & (NY-1), bx = wgid >> log2(NY). With
// round-robin wgid%8 -> XCD dispatch, the NB column-blocks sharing a row-tile of A all have
// wgid === by (mod 8) -> same XCD -> A re-reads hit that XCD's L2 (2 MB working set < 4 MB).
template <int EPI, int K>
__global__ __launch_bounds__(256) void gemm_big(
    const float* __restrict__ A, int lda,
    const __bf16* __restrict__ Whi, const __bf16* __restrict__ Wlo,
    const float* __restrict__ bias,
    float* __restrict__ C, int ldc) {
  const int wave = threadIdx.x >> 6;
  const int lane = threadIdx.x & 63;
  const int m16 = lane & 15;
  const int quad = lane >> 4;
  const int wrow = wave >> 1, wcol = wave & 1;
  const int by = blockIdx.x & 255;  // row-block (NTOT/128 = 256)
  const int bx = blockIdx.x >> 8;   // col-block
  const int row0 = by * 128 + wrow * 64;
  const int col0 = bx * 128 + wcol * 64;
  const int ctb = col0 >> 4;

  f32x4 acc[4][4] = {};
#pragma unroll
  for (int k0 = 0; k0 < K; k0 += 32) {
    bf16x8 ahi[4], alo[4];
#pragma unroll
    for (int mf = 0; mf < 4; ++mf)
      split8(A + (size_t)(row0 + mf * 16 + m16) * lda + k0 + quad * 8, ahi[mf], alo[mf]);
    bf16x8 bhi[4], blo[4];
#pragma unroll
    for (int nf = 0; nf < 4; ++nf) {
      size_t off = ((size_t)(ctb + nf) * (K / 32) + (k0 >> 5)) * 512 + lane * 8;
      bhi[nf] = *(const bf16x8*)(Whi + off);
      blo[nf] = *(const bf16x8*)(Wlo + off);
    }
#pragma unroll
    for (int mf = 0; mf < 4; ++mf)
#pragma unroll
      for (int nf = 0; nf < 4; ++nf) {
        acc[mf][nf] = __builtin_amdgcn_mfma_f32_16x16x32_bf16(ahi[mf], bhi[nf], acc[mf][nf], 0, 0, 0);
        acc[mf][nf] = __builtin_amdgcn_mfma_f32_16x16x32_bf16(ahi[mf], blo[nf], acc[mf][nf], 0, 0, 0);
        acc[mf][nf] = __builtin_amdgcn_mfma_f32_16x16x32_bf16(alo[mf], bhi[nf], acc[mf][nf], 0, 0, 0);
      }
  }
#pragma unroll
  for (int mf = 0; mf < 4; ++mf)
#pragma unroll
    for (int nf = 0; nf < 4; ++nf) {
      int c = col0 + nf * 16 + m16;
      float bj = bias[c];
#pragma unroll
      for (int reg = 0; reg < 4; ++reg) {
        int r = row0 + mf * 16 + quad * 4 + reg;
        float v = acc[mf][nf][reg] + bj;
        if (EPI == 1) v = fmaxf(v, 0.f);
        C[(size_t)r * ldc + c] = v;
      }
    }
}

// ---------------- GEMM + bias + resid + LayerNorm; block 64x128, register A [r12] ----------------
template <int K>
__global__ __launch_bounds__(256) void gemm_ln(
    const float* __restrict__ A, int lda,
    const __bf16* __restrict__ Whi, const __bf16* __restrict__ Wlo,
    const float* __restrict__ bias, const float* __restrict__ resid,
    const float* __restrict__ lng, const float* __restrict__ lnb,
    float* __restrict__ C) {
  const int wave = threadIdx.x >> 6;
  const int lane = threadIdx.x & 63;
  const int m16 = lane & 15;
  const int quad = lane >> 4;
  const int wrow = wave >> 1, wcol = wave & 1;
  const int row0 = blockIdx.y * 64 + wrow * 32;
  const int col0 = wcol * 64;
  const int ctb = wcol * 4;

  f32x4 acc[2][4] = {};
#pragma unroll
  for (int k0 = 0; k0 < K; k0 += 32) {
    bf16x8 ahi[2], alo[2];
#pragma unroll
    for (int mf = 0; mf < 2; ++mf)
      split8(A + (size_t)(row0 + mf * 16 + m16) * lda + k0 + quad * 8, ahi[mf], alo[mf]);
    bf16x8 bhi[4], blo[4];
#pragma unroll
    for (int nf = 0; nf < 4; ++nf) {
      size_t off = ((size_t)(ctb + nf) * (K / 32) + (k0 >> 5)) * 512 + lane * 8;
      bhi[nf] = *(const bf16x8*)(Whi + off);
      blo[nf] = *(const bf16x8*)(Wlo + off);
    }
#pragma unroll
    for (int mf = 0; mf < 2; ++mf)
#pragma unroll
      for (int nf = 0; nf < 4; ++nf) {
        acc[mf][nf] = __builtin_amdgcn_mfma_f32_16x16x32_bf16(ahi[mf], bhi[nf], acc[mf][nf], 0, 0, 0);
        acc[mf][nf] = __builtin_amdgcn_mfma_f32_16x16x32_bf16(ahi[mf], blo[nf], acc[mf][nf], 0, 0, 0);
        acc[mf][nf] = __builtin_amdgcn_mfma_f32_16x16x32_bf16(alo[mf], bhi[nf], acc[mf][nf], 0, 0, 0);
      }
  }
  __shared__ float rs[64][2], rq[64][2];
#pragma unroll
  for (int mf = 0; mf < 2; ++mf)
#pragma unroll
    for (int reg = 0; reg < 4; ++reg) {
      int lr = wrow * 32 + mf * 16 + quad * 4 + reg;
      int gr = blockIdx.y * 64 + lr;
      float s = 0.f, qq = 0.f;
#pragma unroll
      for (int nf = 0; nf < 4; ++nf) {
        int c = col0 + nf * 16 + m16;
        float v = acc[mf][nf][reg] + bias[c] + resid[(size_t)gr * 128 + c];
        acc[mf][nf][reg] = v;
        s += v;
        qq += v * v;
      }
#pragma unroll
      for (int off = 1; off < 16; off <<= 1) {
        s += __shfl_xor(s, off, 64);
        qq += __shfl_xor(qq, off, 64);
      }
      if (m16 == 0) { rs[lr][wcol] = s; rq[lr][wcol] = qq; }
    }
  __syncthreads();
#pragma unroll
  for (int mf = 0; mf < 2; ++mf)
#pragma unroll
    for (int reg = 0; reg < 4; ++reg) {
      int lr = wrow * 32 + mf * 16 + quad * 4 + reg;
      int gr = blockIdx.y * 64 + lr;
      float mean = (rs[lr][0] + rs[lr][1]) * (1.f / 128.f);
      float var = (rq[lr][0] + rq[lr][1]) * (1.f / 128.f) - mean * mean;
      float rstd = rsqrtf(var + EPS_);
#pragma unroll
      for (int nf = 0; nf < 4; ++nf) {
        int c = col0 + nf * 16 + m16;
        C[(size_t)gr * 128 + c] = (acc[mf][nf][reg] - mean) * rstd * lng[c] + lnb[c];
      }
    }
}

// ---------------- FF2 + LN (staged A, K=512) [r12]; SDOT fuses gating dot [r15] ----------------
template <int SDOT>
__global__ __launch_bounds__(256) void ff2_ln(
    const float* __restrict__ A, // ffmid [M][512]
    const __bf16* __restrict__ Whi, const __bf16* __restrict__ Wlo,
    const float* __restrict__ bias, const float* __restrict__ resid,
    const float* __restrict__ lng, const float* __restrict__ lnb,
    float* __restrict__ C,
    const float* __restrict__ bx, float* __restrict__ sdst) {
  const int wave = threadIdx.x >> 6;
  const int lane = threadIdx.x & 63;
  const int m16 = lane & 15;
  const int quad = lane >> 4;
  const int wrow = wave >> 1, wcol = wave & 1;
  const int grow0 = blockIdx.y * 64;
  const int lrow0 = wrow * 32;
  const int col0 = wcol * 64;
  const int ctb = wcol * 4;

  __shared__ float As[64][129];

  f32x4 acc[2][4] = {};
  for (int kc = 0; kc < 4; ++kc) {
    if (kc) __syncthreads();
#pragma unroll
    for (int u = 0; u < 8; ++u) {
      int unit = threadIdx.x + u * 256;
      int r = unit >> 5, c4 = unit & 31;
      float4 v = *(const float4*)(A + (size_t)(grow0 + r) * 512 + kc * 128 + c4 * 4);
      As[r][c4 * 4 + 0] = v.x;
      As[r][c4 * 4 + 1] = v.y;
      As[r][c4 * 4 + 2] = v.z;
      As[r][c4 * 4 + 3] = v.w;
    }
    __syncthreads();
#pragma unroll
    for (int kt = 0; kt < 4; ++kt) {
      bf16x8 ahi[2], alo[2];
#pragma unroll
      for (int mf = 0; mf < 2; ++mf)
        split8(&As[lrow0 + mf * 16 + m16][kt * 32 + quad * 8], ahi[mf], alo[mf]);
      bf16x8 bhi[4], blo[4];
#pragma unroll
      for (int nf = 0; nf < 4; ++nf) {
        size_t off = ((size_t)(ctb + nf) * 16 + (kc * 4 + kt)) * 512 + lane * 8;
        bhi[nf] = *(const bf16x8*)(Whi + off);
        blo[nf] = *(const bf16x8*)(Wlo + off);
      }
#pragma unroll
      for (int mf = 0; mf < 2; ++mf)
#pragma unroll
        for (int nf = 0; nf < 4; ++nf) {
          acc[mf][nf] = __builtin_amdgcn_mfma_f32_16x16x32_bf16(ahi[mf], bhi[nf], acc[mf][nf], 0, 0, 0);
          acc[mf][nf] = __builtin_amdgcn_mfma_f32_16x16x32_bf16(ahi[mf], blo[nf], acc[mf][nf], 0, 0, 0);
          acc[mf][nf] = __builtin_amdgcn_mfma_f32_16x16x32_bf16(alo[mf], bhi[nf], acc[mf][nf], 0, 0, 0);
        }
    }
  }
  __shared__ float rs[64][2], rq[64][2];
  __shared__ float sd[64][2];
#pragma unroll
  for (int mf = 0; mf < 2; ++mf)
#pragma unroll
    for (int reg = 0; reg < 4; ++reg) {
      int lr = lrow0 + mf * 16 + quad * 4 + reg;
      int gr = grow0 + lr;
      float s = 0.f, qq = 0.f;
#pragma unroll
      for (int nf = 0; nf < 4; ++nf) {
        int c = col0 + nf * 16 + m16;
        float v = acc[mf][nf][reg] + bias[c] + resid[(size_t)gr * 128 + c];
        acc[mf][nf][reg] = v;
        s += v;
        qq += v * v;
      }
#pragma unroll
      for (int off = 1; off < 16; off <<= 1) {
        s += __shfl_xor(s, off, 64);
        qq += __shfl_xor(qq, off, 64);
      }
      if (m16 == 0) { rs[lr][wcol] = s; rq[lr][wcol] = qq; }
    }
  __syncthreads();
#pragma unroll
  for (int mf = 0; mf < 2; ++mf)
#pragma unroll
    for (int reg = 0; reg < 4; ++reg) {
      int lr = lrow0 + mf * 16 + quad * 4 + reg;
      int gr = grow0 + lr;
      float mean = (rs[lr][0] + rs[lr][1]) * (1.f / 128.f);
      float var = (rq[lr][0] + rq[lr][1]) * (1.f / 128.f) - mean * mean;
      float rstd = rsqrtf(var + EPS_);
      float sdp = 0.f;
#pragma unroll
      for (int nf = 0; nf < 4; ++nf) {
        int c = col0 + nf * 16 + m16;
        float v = (acc[mf][nf][reg] - mean) * rstd * lng[c] + lnb[c];
        C[(size_t)gr * 128 + c] = v;
        if (SDOT) sdp += v * bx[(size_t)gr * 128 + c];
      }
      if (SDOT) {
#pragma unroll
        for (int off = 1; off < 16; off <<= 1) sdp += __shfl_xor(sdp, off, 64);
        if (m16 == 0) sd[lr][wcol] = sdp;
      }
    }
  if (SDOT) {
    __syncthreads();
    if (threadIdx.x < 64) {
      int lr = threadIdx.x;
      int gr = grow0 + lr;
      float sv = sd[lr][0] + sd[lr][1];
      int t = gr & (T_ - 1);
      int bn = gr >> 7;
      int n = bn & (NA - 1);
      int b = bn >> 6;
      sdst[(size_t)b * NN + t * NA + n] = sv;
    }
  }
}

// ---------------- FUSED QKV-GEMM + attention [r25: head-major decode for XCD L2 sharing] ----------------
// r24 structure + one change: decode h = wgid>>8, bn = wgid&255 (was bn*8+h). With round-robin
// wgid%8 -> XCD dispatch, the 8 head-blocks sharing a bn's 64KB A-tile now all land on the SAME
// XCD (wgid === bn mod 8); per-XCD be working set = 32 bn x 64KB = 2MB < 4MB L2, so the 8x
// redundant A reads hit L2 instead of HBM (r24 measured FETCH 65.9MB vs ~17MB ideal).
// Pure index remap — no math, layout, or accumulation change.
__global__ __launch_bounds__(256) void attn_fused(
    const float* __restrict__ A,       // be [NTOT][128]
    const __bf16* __restrict__ Whi, const __bf16* __restrict__ Wlo, // layer qkv segment
    const float* __restrict__ pb,      // packed qkv bias [384]
    float* __restrict__ O) {           // [NTOT][128]
  const int h = blockIdx.x >> 8;      // head-major
  const int bn = blockIdx.x & 255;    // same-bn blocks share an XCD
  const int wave = threadIdx.x >> 6;
  const int lane = threadIdx.x & 63;
  const int m16 = lane & 15;
  const int quad = lane >> 4;
  const int row0 = wave * 32;
  const float* Ab = A + (size_t)bn * T_ * 128;

  __shared__ __bf16 Plds[4][32][136];
  __shared__ __bf16 KVH[8][32][8], KVL[8][32][8]; // K then (post-QK^T) V, time-shared
  __bf16* QHw = &Plds[wave][0][0];                // wave-private Q: [2][32][8] (aliased)
  __bf16* QLw = QHw + 512;
  __bf16* kvh = &KVH[0][0][0];
  __bf16* kvl = &KVL[0][0][0];

  // ---- mini-GEMM: rows [row0, row0+32) x {Q,K,V} cols [h*16, h*16+16)
  f32x4 qkv[2][3] = {}; // [mf][seg]
#pragma unroll
  for (int k0 = 0; k0 < 128; k0 += 32) {
    bf16x8 ahi[2], alo[2];
#pragma unroll
    for (int mf = 0; mf < 2; ++mf)
      split8(Ab + (size_t)(row0 + mf * 16 + m16) * 128 + k0 + quad * 8, ahi[mf], alo[mf]);
    bf16x8 bhi[3], blo[3];
#pragma unroll
    for (int s = 0; s < 3; ++s) {
      size_t off = ((size_t)(s * 8 + h) * 4 + (k0 >> 5)) * 512 + lane * 8; // ctb = s*8+h
      bhi[s] = *(const bf16x8*)(Whi + off);
      blo[s] = *(const bf16x8*)(Wlo + off);
    }
#pragma unroll
    for (int mf = 0; mf < 2; ++mf)
#pragma unroll
      for (int s = 0; s < 3; ++s) {
        qkv[mf][s] = __builtin_amdgcn_mfma_f32_16x16x32_bf16(ahi[mf], bhi[s], qkv[mf][s], 0, 0, 0);
        qkv[mf][s] = __builtin_amdgcn_mfma_f32_16x16x32_bf16(ahi[mf], blo[s], qkv[mf][s], 0, 0, 0);
        qkv[mf][s] = __builtin_amdgcn_mfma_f32_16x16x32_bf16(alo[mf], bhi[s], qkv[mf][s], 0, 0, 0);
      }
  }

  // ---- stage Q (wave-private) + K (shared); V stays in registers until after QK^T
#pragma unroll
  for (int mf = 0; mf < 2; ++mf)
#pragma unroll
    for (int reg = 0; reg < 4; ++reg) {
      const int tl = mf * 16 + quad * 4 + reg; // local row 0..31
      const int t = row0 + tl;                 // block row 0..127
      const int dh = m16;
      { // Q -> wave-private
        float v = qkv[mf][0][reg] + pb[h * 16 + dh];
        __bf16 hh = (__bf16)v;
        __bf16 ll = (__bf16)(v - (float)hh);
        int idx = mf * 256 + ((dh >> 3) * 16 + (tl & 15)) * 8 + (dh & 7);
        QHw[idx] = hh;
        QLw[idx] = ll;
      }
      { // K -> shared (K layout: [t>>4][(dh>>3)*16 + (t&15)][dh&7])
        float v = qkv[mf][1][reg] + pb[128 + h * 16 + dh];
        __bf16 hh = (__bf16)v;
        __bf16 ll = (__bf16)(v - (float)hh);
        int idx = ((t >> 4) * 32 + (dh >> 3) * 16 + (t & 15)) * 8 + (dh & 7);
        kvh[idx] = hh;
        kvl[idx] = ll;
      }
    }

  // ---- read own Q A-frags back (wave-private; same-wave LDS dependency)
  bf16x8 qhi[2], qlo[2];
#pragma unroll
  for (int mf = 0; mf < 2; ++mf) {
    if (quad < 2) {
      int idx = mf * 256 + (quad * 16 + m16) * 8;
      qhi[mf] = *(const bf16x8*)&QHw[idx];
      qlo[mf] = *(const bf16x8*)&QLw[idx];
    } else {
#pragma unroll
      for (int j = 0; j < 8; ++j) { qhi[mf][j] = (__bf16)0.f; qlo[mf][j] = (__bf16)0.f; }
    }
  }
  __syncthreads(); // K staging visible to all waves

  f32x4 acc[2][8] = {};
#pragma unroll
  for (int nf = 0; nf < 8; ++nf) {
    bf16x8 khi, klo;
    if (quad < 2) {
      khi = *(const bf16x8*)&kvh[(nf * 32 + lane) * 8]; // lane in [0,32)
      klo = *(const bf16x8*)&kvl[(nf * 32 + lane) * 8];
    } else {
#pragma unroll
      for (int j = 0; j < 8; ++j) { khi[j] = (__bf16)0.f; klo[j] = (__bf16)0.f; }
    }
#pragma unroll
    for (int mf = 0; mf < 2; ++mf) {
      acc[mf][nf] = __builtin_amdgcn_mfma_f32_16x16x32_bf16(qhi[mf], khi, acc[mf][nf], 0, 0, 0);
      acc[mf][nf] = __builtin_amdgcn_mfma_f32_16x16x32_bf16(qhi[mf], klo, acc[mf][nf], 0, 0, 0);
      acc[mf][nf] = __builtin_amdgcn_mfma_f32_16x16x32_bf16(qlo[mf], khi, acc[mf][nf], 0, 0, 0);
    }
  }
  __syncthreads(); // all waves done reading K -> region reusable for V

  // ---- stage V into the K region (V layout: [(t>>5)*64 + (rem>>3)*16 + dh][rem&7])
#pragma unroll
  for (int mf = 0; mf < 2; ++mf)
#pragma unroll
    for (int reg = 0; reg < 4; ++reg) {
      const int t = row0 + mf * 16 + quad * 4 + reg;
      const int dh = m16;
      float v = qkv[mf][2][reg] + pb[256 + h * 16 + dh];
      __bf16 hh = (__bf16)v;
      __bf16 ll = (__bf16)(v - (float)hh);
      int kc = t >> 5, rem = t & 31;
      int idx = (kc * 64 + (rem >> 3) * 16 + dh) * 8 + (rem & 7);
      kvh[idx] = hh;
      kvl[idx] = ll;
    }

  // ---- softmax (register-only; overlaps other waves' V stores)
  const float scale = 0.25f;
#pragma unroll
  for (int mf = 0; mf < 2; ++mf)
#pragma unroll
    for (int reg = 0; reg < 4; ++reg) {
      float mx = -1e30f;
#pragma unroll
      for (int nf = 0; nf < 8; ++nf) mx = fmaxf(mx, acc[mf][nf][reg]);
#pragma unroll
      for (int off = 1; off < 16; off <<= 1) mx = fmaxf(mx, __shfl_xor(mx, off, 64));
      float sum = 0.f;
#pragma unroll
      for (int nf = 0; nf < 8; ++nf) {
        float e = __expf((acc[mf][nf][reg] - mx) * scale);
        acc[mf][nf][reg] = e;
        sum += e;
      }
#pragma unroll
      for (int off = 1; off < 16; off <<= 1) sum += __shfl_xor(sum, off, 64);
      float inv = 1.f / sum;
#pragma unroll
      for (int nf = 0; nf < 8; ++nf) acc[mf][nf][reg] *= inv;
    }
  __syncthreads(); // V staging visible to all waves

#pragma unroll
  for (int mf = 0; mf < 2; ++mf)
#pragma unroll
    for (int nf = 0; nf < 8; ++nf)
#pragma unroll
      for (int reg = 0; reg < 4; ++reg)
        Plds[wave][mf * 16 + quad * 4 + reg][nf * 16 + m16] = (__bf16)acc[mf][nf][reg];

  f32x4 oacc[2] = {};
#pragma unroll
  for (int kc = 0; kc < 4; ++kc) {
    bf16x8 pa0 = *(const bf16x8*)&Plds[wave][m16][kc * 32 + quad * 8];
    bf16x8 pa1 = *(const bf16x8*)&Plds[wave][16 + m16][kc * 32 + quad * 8];
    bf16x8 vhi = *(const bf16x8*)&kvh[(kc * 64 + lane) * 8];
    bf16x8 vlo = *(const bf16x8*)&kvl[(kc * 64 + lane) * 8];
    oacc[0] = __builtin_amdgcn_mfma_f32_16x16x32_bf16(pa0, vhi, oacc[0], 0, 0, 0);
    oacc[0] = __builtin_amdgcn_mfma_f32_16x16x32_bf16(pa0, vlo, oacc[0], 0, 0, 0);
    oacc[1] = __builtin_amdgcn_mfma_f32_16x16x32_bf16(pa1, vhi, oacc[1], 0, 0, 0);
    oacc[1] = __builtin_amdgcn_mfma_f32_16x16x32_bf16(pa1, vlo, oacc[1], 0, 0, 0);
  }

#pragma unroll
  for (int mf = 0; mf < 2; ++mf)
#pragma unroll
    for (int reg = 0; reg < 4; ++reg) {
      int r = row0 + mf * 16 + quad * 4 + reg;
      O[((size_t)bn * T_ + r) * 128 + h * 16 + m16] = oacc[mf][reg];
    }
}

// ---------------- edge scatter ----------------
__global__ __launch_bounds__(256) void scatter_kernel(
    const float* __restrict__ s, const int* __restrict__ ei,
    const float* __restrict__ ew, float* __restrict__ g) {
  int idx = blockIdx.x * 256 + threadIdx.x;
  if (idx >= B_ * E_) return;
  int b = idx >> 16;
  int e = idx & (E_ - 1);
  int src = ei[(size_t)b * 2 * E_ + e];
  int dst = ei[(size_t)b * 2 * E_ + E_ + e];
  float w = ew[(size_t)b * E_ + e];
  atomicAdd(&g[(size_t)b * NN + dst], w * s[(size_t)b * NN + src]);
}

// ---------------- partial sums for global mean/var ----------------
__global__ __launch_bounds__(256) void stats_partial(
    const float* __restrict__ g, float* __restrict__ st) {
  int i = blockIdx.x * 256 + threadIdx.x;
  float v = g[i];
  float sum = v, sq = v * v;
#pragma unroll
  for (int off = 32; off; off >>= 1) {
    sum += __shfl_down(sum, off, 64);
    sq += __shfl_down(sq, off, 64);
  }
  __shared__ float s1[4], s2[4];
  int w = threadIdx.x >> 6;
  if ((threadIdx.x & 63) == 0) { s1[w] = sum; s2[w] = sq; }
  __syncthreads();
  if (threadIdx.x == 0) {
    atomicAdd(&st[0], s1[0] + s1[1] + s1[2] + s1[3]);
    atomicAdd(&st[1], s2[0] + s2[1] + s2[2] + s2[3]);
  }
}

// ---------------- final (fp32 out) ----------------
__global__ __launch_bounds__(256) void final_kernel(
    const float* __restrict__ g, const float* __restrict__ st,
    const float* __restrict__ bng, const float* __restrict__ bnb,
    const float* __restrict__ lw, const float* __restrict__ lb,
    float* __restrict__ out) {
  int idx = blockIdx.x * 256 + threadIdx.x;
  if (idx >= NTOT * D_) return;
  int d = idx & (D_ - 1);
  int r = idx >> 7;
  int t = r & (T_ - 1);
  int bn = r >> 7;
  int n = bn & (NA - 1);
  int b = bn >> 6;
  const float invn = 1.f / (float)(B_ * NN);
  float m = st[0] * invn;
  float var = st[1] * invn - m * m;
  float rs = rsqrtf(var + EPS_);
  float gv = g[(size_t)b * NN + t * NA + n];
  float val = (gv - m) * rs * bng[0] + bnb[0];
  out[idx] = val * lw[d] + lb[d];
}

extern "C" void kernel_launch(void* const* d_in, const int* in_sizes, int n_in,
                              void* d_out, int out_size, void* d_ws, size_t ws_size,
                              hipStream_t stream) {
  const float* hist = (const float*)d_in[0];
  const int* eidx = (const int*)d_in[1];
  const float* ew = (const float*)d_in[2];
  const float* hw = (const float*)d_in[3];
  const float* hb = (const float*)d_in[4];
  const float* wq = (const float*)d_in[5];
  const float* bq = (const float*)d_in[6];
  const float* wk = (const float*)d_in[7];
  const float* bk = (const float*)d_in[8];
  const float* wv = (const float*)d_in[9];
  const float* bv = (const float*)d_in[10];
  const float* wo = (const float*)d_in[11];
  const float* bo = (const float*)d_in[12];
  const float* ln1g = (const float*)d_in[13];
  const float* ln1b = (const float*)d_in[14];
  const float* w1 = (const float*)d_in[15];
  const float* b1 = (const float*)d_in[16];
  const float* w2 = (const float*)d_in[17];
  const float* b2 = (const float*)d_in[18];
  const float* ln2g = (const float*)d_in[19];
  const float* ln2b = (const float*)d_in[20];
  const float* bng = (const float*)d_in[21];
  const float* bnb = (const float*)d_in[22];
  const float* lgw = (const float*)d_in[23];
  const float* lgb = (const float*)d_in[24];
  float* out = (float*)d_out;

  float* ws = (float*)d_ws;
  const size_t NE = NE_;
  float* bx = ws + 0 * NE;
  float* be = ws + 1 * NE;
  float* h1 = ws + 2 * NE;
  float* obuf = ws + 3 * NE;  // attention output [row][128]
  float* ffmid = ws + 3 * NE; // 4NE, overlaps dead obuf (sequential deps)
  float* bs_ = ws + 7 * NE;
  float* bg_ = bs_ + NTOT;
  float* bst = bg_ + NTOT;
  float* pbias = bst + 2;
  const int LW = 196608;
  __bf16* whiB = (__bf16*)(pbias + L_ * QLD);
  __bf16* wloB = whiB + (size_t)L_ * LW;

  convert_weights<<<(L_ * LW + 255) / 256, 256, 0, stream>>>(
      wq, wk, wv, wo, w1, w2, whiB, wloB);
  bias_pack<<<(L_ * QLD + 255) / 256, 256, 0, stream>>>(bq, bk, bv, pbias);
  embed_kernel<<<(NTOT * D_) / 256, 256, 0, stream>>>(hist, hw, hb, bx, be);

  for (int l = 0; l < L_; ++l) {
    const __bf16* hiL = whiB + (size_t)l * LW;
    const __bf16* loL = wloB + (size_t)l * LW;
    attn_fused<<<B_ * NA * H_, 256, 0, stream>>>(
        be, hiL, loL, pbias + l * QLD, obuf);
    gemm_ln<128><<<dim3(1, NTOT / 64), 256, 0, stream>>>(
        obuf, 128, hiL + 49152, loL + 49152, bo + l * D_, be,
        ln1g + l * D_, ln1b + l * D_, h1);
    gemm_big<1, 128><<<4 * (NTOT / 128), 256, 0, stream>>>(
        h1, 128, hiL + 65536, loL + 65536, b1 + l * DFF, ffmid, 512);
    if (l < L_ - 1) {
      ff2_ln<0><<<dim3(1, NTOT / 64), 256, 0, stream>>>(
          ffmid, hiL + 131072, loL + 131072, b2 + l * D_, h1,
          ln2g + l * D_, ln2b + l * D_, be, nullptr, nullptr);
    } else {
      ff2_ln<1><<<dim3(1, NTOT / 64), 256, 0, stream>>>(
          ffmid, hiL + 131072, loL + 131072, b2 + l * D_, h1,
          ln2g + l * D_, ln2b + l * D_, be, bx, bs_);
    }
  }

  hipMemsetAsync(bg_, 0, ((size_t)B_ * NN + 2) * sizeof(float), stream);
  scatter_kernel<<<(B_ * E_) / 256, 256, 0, stream>>>(bs_, eidx, ew, bg_);
  stats_partial<<<(B_ * NN) / 256, 256, 0, stream>>>(bg_, bst);
  final_kernel<<<(NTOT * D_) / 256, 256, 0, stream>>>(bg_, bst, bng, bnb, lgw, lgb, out);
}